// Round 1
// baseline (553.500 us; speedup 1.0000x reference)
//
#include <hip/hip_runtime.h>

// Problem constants
#define BB  2
#define SS  2048
#define DD  2048
#define HH  16
#define HDD 128
#define BSR 4096   // BB*SS rows

using short8  = __attribute__((ext_vector_type(8))) short;
using floatx4 = __attribute__((ext_vector_type(4))) float;

__device__ __forceinline__ float bf2f(unsigned short u) {
  return __uint_as_float(((unsigned int)u) << 16);
}
__device__ __forceinline__ unsigned short f2bf(float f) {
  unsigned int u = __float_as_uint(f);
  u += 0x7fffu + ((u >> 16) & 1u);   // round-to-nearest-even
  return (unsigned short)(u >> 16);
}
// async global->LDS, 16 bytes per lane. LDS dest must be wave-uniform base + lane*16.
__device__ __forceinline__ void gl_lds16(const void* g, void* l) {
  __builtin_amdgcn_global_load_lds(
      (__attribute__((address_space(1))) void*)g,
      (__attribute__((address_space(3))) void*)l, 16, 0, 0);
}

// ---------------- weight transpose + bf16 convert: Out[f][d] = W[d][f] ----------------
__global__ __launch_bounds__(256) void transpose_w(
    const float* __restrict__ Wq, const float* __restrict__ Wk,
    const float* __restrict__ Wv, const float* __restrict__ Wo,
    unsigned short* __restrict__ wqkvt, unsigned short* __restrict__ wot)
{
  __shared__ float tile[32][33];
  const float* W; unsigned short* Out;
  int z = blockIdx.z;
  if      (z == 0) { W = Wq; Out = wqkvt; }
  else if (z == 1) { W = Wk; Out = wqkvt + (size_t)DD * DD; }
  else if (z == 2) { W = Wv; Out = wqkvt + 2 * (size_t)DD * DD; }
  else             { W = Wo; Out = wot; }
  int tx = threadIdx.x, ty = threadIdx.y;
  int d0 = blockIdx.y * 32, f0 = blockIdx.x * 32;
#pragma unroll
  for (int i = 0; i < 4; i++)
    tile[ty + i * 8][tx] = W[(size_t)(d0 + ty + i * 8) * DD + f0 + tx];
  __syncthreads();
#pragma unroll
  for (int i = 0; i < 4; i++)
    Out[(size_t)(f0 + ty + i * 8) * DD + d0 + tx] = f2bf(tile[tx][ty + i * 8]);
}

// ---------------- x -> bf16 ----------------
__global__ __launch_bounds__(256) void conv_x(const float* __restrict__ x,
                                              unsigned short* __restrict__ xb)
{
  size_t i = ((size_t)blockIdx.x * 256 + threadIdx.x) * 4;
  float4 v = *(const float4*)(x + i);
  ushort4 o;
  o.x = f2bf(v.x); o.y = f2bf(v.y); o.z = f2bf(v.z); o.w = f2bf(v.w);
  *(ushort4*)(xb + i) = o;
}

// ---------------- bf16 MFMA GEMM, B^T layout (m97 recipe) ----------------
// C[M,N] = A[M,K] * Bt[N,K]^T (+bias). 128x128 tile, BK=32, 256 threads.
template <bool OUTF32>
__global__ __launch_bounds__(256) void gemm_bt(
    const unsigned short* __restrict__ A, const unsigned short* __restrict__ Bt,
    const float* __restrict__ bias, void* __restrict__ Cout,
    int M, int N, int K)
{
  __shared__ unsigned short As[128 * 32];
  __shared__ unsigned short Bs[128 * 32];
  int t = threadIdx.x;
  int m0 = blockIdx.y * 128, n0 = blockIdx.x * 128;
  int w = t >> 6, lane = t & 63, qd = lane >> 4, l16 = lane & 15;
  int wm = (w >> 1) * 64, wn = (w & 1) * 64;
  floatx4 zero4 = {0.f, 0.f, 0.f, 0.f};
  floatx4 acc[4][4];
#pragma unroll
  for (int i = 0; i < 4; i++)
#pragma unroll
    for (int j = 0; j < 4; j++) acc[i][j] = zero4;

  const unsigned short* Ab = A  + (size_t)(m0 + (t >> 2)) * K + (t & 3) * 8;
  const unsigned short* Bb = Bt + (size_t)(n0 + (t >> 2)) * K + (t & 3) * 8;
  size_t half = (size_t)64 * K;

  for (int k0 = 0; k0 < K; k0 += 32) {
    __syncthreads();
    gl_lds16(Ab + k0,        &As[t * 8]);
    gl_lds16(Ab + half + k0, &As[2048 + t * 8]);
    gl_lds16(Bb + k0,        &Bs[t * 8]);
    gl_lds16(Bb + half + k0, &Bs[2048 + t * 8]);
    __syncthreads();
    short8 af[4], bfr[4];
#pragma unroll
    for (int i = 0; i < 4; i++)
      af[i] = *(const short8*)&As[(wm + i * 16 + l16) * 32 + qd * 8];
#pragma unroll
    for (int j = 0; j < 4; j++)
      bfr[j] = *(const short8*)&Bs[(wn + j * 16 + l16) * 32 + qd * 8];
#pragma unroll
    for (int i = 0; i < 4; i++)
#pragma unroll
      for (int j = 0; j < 4; j++)
        acc[i][j] = __builtin_amdgcn_mfma_f32_16x16x32_bf16(af[i], bfr[j], acc[i][j], 0, 0, 0);
  }

#pragma unroll
  for (int i = 0; i < 4; i++)
#pragma unroll
    for (int j = 0; j < 4; j++) {
      int row = m0 + wm + i * 16 + qd * 4;
      int col = n0 + wn + j * 16 + l16;
      float bsv = bias ? bias[col] : 0.f;
#pragma unroll
      for (int r = 0; r < 4; r++) {
        float v = acc[i][j][r] + bsv;
        if (OUTF32) ((float*)Cout)[(size_t)(row + r) * N + col] = v;
        else ((unsigned short*)Cout)[(size_t)(row + r) * N + col] = f2bf(v);
      }
    }
}

// ---------------- RoPE + bias + rearrange q,k: qkv[BS,3D] -> [B,H,S,HD] ----------------
__global__ __launch_bounds__(256) void rope_qk(
    const unsigned short* __restrict__ qkv, const float* __restrict__ bq,
    const float* __restrict__ bk, unsigned short* __restrict__ q_r,
    unsigned short* __restrict__ k_r)
{
  int lin = blockIdx.x * 256 + threadIdx.x;
  int i = lin & 63;
  int s = (lin >> 6) & (SS - 1);
  int h = (lin >> 17) & (HH - 1);
  int b = lin >> 21;
  size_t row = (size_t)(b * SS + s) * (3 * DD);
  int f = h * HDD + i;
  float q1 = bf2f(qkv[row + f])            + bq[f];
  float q2 = bf2f(qkv[row + f + 64])       + bq[f + 64];
  float k1 = bf2f(qkv[row + DD + f])       + bk[f];
  float k2 = bf2f(qkv[row + DD + f + 64])  + bk[f + 64];
  float inv = powf(10000.f, -(float)i * (1.f / 64.f));
  float ang = (float)s * inv;
  float sn, c;
  sincosf(ang, &sn, &c);
  size_t ob = ((size_t)(b * HH + h) * SS + s) * HDD;
  q_r[ob + i]      = f2bf(q1 * c - q2 * sn);
  q_r[ob + i + 64] = f2bf(q1 * sn + q2 * c);
  k_r[ob + i]      = f2bf(k1 * c - k2 * sn);
  k_r[ob + i + 64] = f2bf(k1 * sn + k2 * c);
}

// ---------------- V transpose: qkv v-part -> v_t[B,H,HD,S] (+bias) ----------------
__global__ __launch_bounds__(256) void v_transpose(
    const unsigned short* __restrict__ qkv, const float* __restrict__ bv,
    unsigned short* __restrict__ v_t)
{
  __shared__ float tile[32][33];
  int bh = blockIdx.z; int b = bh >> 4, h = bh & 15;
  int s0 = blockIdx.x * 32, d0 = blockIdx.y * 32;
  int tx = threadIdx.x, ty = threadIdx.y;
#pragma unroll
  for (int i = 0; i < 4; i++) {
    int s = s0 + ty + i * 8, dh = d0 + tx;
    tile[ty + i * 8][tx] =
        bf2f(qkv[(size_t)(b * SS + s) * (3 * DD) + 2 * DD + h * HDD + dh]) + bv[h * HDD + dh];
  }
  __syncthreads();
#pragma unroll
  for (int i = 0; i < 4; i++)
    v_t[((size_t)(b * HH + h) * HDD + d0 + ty + i * 8) * SS + s0 + tx] =
        f2bf(tile[tx][ty + i * 8]);
}

// ---------------- flash attention ----------------
// grid: (S/64, B*H). 256 threads = 4 waves; wave w owns q rows [w*16, w*16+16).
// LDS K/V/P tiles XOR-chunk-swizzled (16B chunks) to avoid 16-way bank conflicts.
__global__ __launch_bounds__(256) void attn_kernel(
    const unsigned short* __restrict__ q_r, const unsigned short* __restrict__ k_r,
    const unsigned short* __restrict__ v_t, unsigned short* __restrict__ aout)
{
  __shared__ unsigned short Ks[64 * 128];   // [key][hd], swizzled chunks
  __shared__ unsigned short Vs[128 * 64];   // [hd][key], swizzled chunks
  __shared__ unsigned short Ps[4][16 * 64]; // per-wave P [qrow][key], swizzled
  int t = threadIdx.x, w = t >> 6, lane = t & 63, qd = lane >> 4, l16 = lane & 15;
  int bh = blockIdx.y, q0 = blockIdx.x * 64;
  const unsigned short* qb = q_r + (size_t)bh * SS * HDD;
  const unsigned short* kb = k_r + (size_t)bh * SS * HDD;
  const unsigned short* vb = v_t + (size_t)bh * HDD * SS;

  short8 aq[4];
#pragma unroll
  for (int ks = 0; ks < 4; ks++)
    aq[ks] = *(const short8*)&qb[(size_t)(q0 + w * 16 + l16) * HDD + ks * 32 + qd * 8];

  float m_i[4], l_i[4];
  floatx4 zero4 = {0.f, 0.f, 0.f, 0.f};
  floatx4 o[8];
#pragma unroll
  for (int r = 0; r < 4; r++) { m_i[r] = -1e30f; l_i[r] = 0.f; }
#pragma unroll
  for (int n = 0; n < 8; n++) o[n] = zero4;

  for (int kt = 0; kt < SS; kt += 64) {
    __syncthreads();
#pragma unroll
    for (int c = 0; c < 4; c++) {       // stage K tile: 64 rows x 128 elems
      int flat = c * 256 + t;
      int r = flat >> 4, cc = flat & 15;
      gl_lds16(kb + (size_t)(kt + r) * HDD + (cc ^ (r & 15)) * 8, &Ks[flat * 8]);
    }
#pragma unroll
    for (int c = 0; c < 4; c++) {       // stage V^T tile: 128 rows x 64 elems
      int flat = c * 256 + t;
      int r = flat >> 3, cc = flat & 7;
      gl_lds16(vb + (size_t)r * SS + kt + (cc ^ (r & 7)) * 8, &Vs[flat * 8]);
    }
    __syncthreads();

    floatx4 sc[4];
#pragma unroll
    for (int j = 0; j < 4; j++) sc[j] = zero4;
#pragma unroll
    for (int j = 0; j < 4; j++)
#pragma unroll
      for (int ks = 0; ks < 4; ks++) {
        int krow = j * 16 + l16;
        int chunk = ks * 4 + qd;
        short8 bk8 = *(const short8*)&Ks[krow * 128 + ((chunk ^ (krow & 15)) * 8)];
        sc[j] = __builtin_amdgcn_mfma_f32_16x16x32_bf16(aq[ks], bk8, sc[j], 0, 0, 0);
      }

    const float scale = 0.08838834764831845f;  // 1/sqrt(128)
    float rmax[4];
#pragma unroll
    for (int r = 0; r < 4; r++) rmax[r] = -1e30f;
#pragma unroll
    for (int j = 0; j < 4; j++)
#pragma unroll
      for (int r = 0; r < 4; r++) {
        sc[j][r] *= scale;
        rmax[r] = fmaxf(rmax[r], sc[j][r]);
      }
#pragma unroll
    for (int mask = 1; mask < 16; mask <<= 1)
#pragma unroll
      for (int r = 0; r < 4; r++)
        rmax[r] = fmaxf(rmax[r], __shfl_xor(rmax[r], mask, 64));

    float alpha[4], rsum[4];
#pragma unroll
    for (int r = 0; r < 4; r++) {
      float mn = fmaxf(m_i[r], rmax[r]);
      alpha[r] = __expf(m_i[r] - mn);
      m_i[r] = mn;
      rsum[r] = 0.f;
    }
#pragma unroll
    for (int j = 0; j < 4; j++)
#pragma unroll
      for (int r = 0; r < 4; r++) {
        float p = __expf(sc[j][r] - m_i[r]);
        rsum[r] += p;
        int prow = qd * 4 + r, pcol = j * 16 + l16;
        int chunk = pcol >> 3;
        Ps[w][prow * 64 + ((chunk ^ (prow & 7)) * 8) + (pcol & 7)] = f2bf(p);
      }
#pragma unroll
    for (int mask = 1; mask < 16; mask <<= 1)
#pragma unroll
      for (int r = 0; r < 4; r++) rsum[r] += __shfl_xor(rsum[r], mask, 64);
#pragma unroll
    for (int r = 0; r < 4; r++) l_i[r] = l_i[r] * alpha[r] + rsum[r];
#pragma unroll
    for (int n = 0; n < 8; n++)
#pragma unroll
      for (int r = 0; r < 4; r++) o[n][r] *= alpha[r];

    short8 ap[2];
#pragma unroll
    for (int ks = 0; ks < 2; ks++) {
      int chunk = ks * 4 + qd;
      ap[ks] = *(const short8*)&Ps[w][l16 * 64 + ((chunk ^ (l16 & 7)) * 8)];
    }
#pragma unroll
    for (int n = 0; n < 8; n++)
#pragma unroll
      for (int ks = 0; ks < 2; ks++) {
        int vrow = n * 16 + l16;
        int chunk = ks * 4 + qd;
        short8 bv8 = *(const short8*)&Vs[vrow * 64 + ((chunk ^ (vrow & 7)) * 8)];
        o[n] = __builtin_amdgcn_mfma_f32_16x16x32_bf16(ap[ks], bv8, o[n], 0, 0, 0);
      }
  }

  int b = bh >> 4, h = bh & 15;
#pragma unroll
  for (int r = 0; r < 4; r++) {
    int srow = q0 + w * 16 + qd * 4 + r;
    float inv_l = 1.f / l_i[r];
    size_t base = ((size_t)(b * SS + srow)) * DD + h * HDD;
#pragma unroll
    for (int n = 0; n < 8; n++)
      aout[base + n * 16 + l16] = f2bf(o[n][r] * inv_l);
  }
}

// ---------------- launch ----------------
extern "C" void kernel_launch(void* const* d_in, const int* in_sizes, int n_in,
                              void* d_out, int out_size, void* d_ws, size_t ws_size,
                              hipStream_t stream) {
  const float* x  = (const float*)d_in[0];
  const float* Wq = (const float*)d_in[1];
  const float* bq = (const float*)d_in[2];
  const float* Wk = (const float*)d_in[3];
  const float* bk = (const float*)d_in[4];
  const float* Wv = (const float*)d_in[5];
  const float* bv = (const float*)d_in[6];
  const float* Wo = (const float*)d_in[7];
  const float* bo = (const float*)d_in[8];
  float* out = (float*)d_out;

  char* ws = (char*)d_ws;
  // workspace layout (bytes); attn_out aliases xb (xb dead after QKV GEMM)
  unsigned short* xb      = (unsigned short*)(ws + 0);            // [BS,D] bf16, 16 MB
  unsigned short* wqkvt   = (unsigned short*)(ws + 16777216);     // [3D,D] bf16, 24 MB
  unsigned short* wot     = (unsigned short*)(ws + 41943040);     // [D,D]  bf16, 8 MB
  unsigned short* qkv     = (unsigned short*)(ws + 50331648);     // [BS,3D] bf16, 48 MB
  unsigned short* q_r     = (unsigned short*)(ws + 100663296);    // [B,H,S,HD] 16 MB
  unsigned short* k_r     = (unsigned short*)(ws + 117440512);    // [B,H,S,HD] 16 MB
  unsigned short* v_t     = (unsigned short*)(ws + 134217728);    // [B,H,HD,S] 16 MB
  unsigned short* attn_o  = xb;                                   // alias

  transpose_w<<<dim3(DD / 32, DD / 32, 4), dim3(32, 8), 0, stream>>>(
      Wq, Wk, Wv, Wo, wqkvt, wot);
  conv_x<<<dim3((BSR * DD) / 1024), dim3(256), 0, stream>>>(x, xb);
  gemm_bt<false><<<dim3(3 * DD / 128, BSR / 128), dim3(256), 0, stream>>>(
      xb, wqkvt, nullptr, qkv, BSR, 3 * DD, DD);
  rope_qk<<<dim3((BB * HH * SS * 64) / 256), dim3(256), 0, stream>>>(
      qkv, bq, bk, q_r, k_r);
  v_transpose<<<dim3(SS / 32, HDD / 32, BB * HH), dim3(32, 8), 0, stream>>>(
      qkv, bv, v_t);
  attn_kernel<<<dim3(SS / 64, BB * HH), dim3(256), 0, stream>>>(
      q_r, k_r, v_t, attn_o);
  gemm_bt<true><<<dim3(DD / 128, BSR / 128), dim3(256), 0, stream>>>(
      attn_o, wot, bo, out, BSR, DD, DD);
}

// Round 2
// 500.479 us; speedup vs baseline: 1.1059x; 1.1059x over previous
//
#include <hip/hip_runtime.h>

// Problem constants
#define BB  2
#define SS  2048
#define DD  2048
#define HH  16
#define HDD 128
#define BSR 4096   // BB*SS rows

using short8  = __attribute__((ext_vector_type(8))) short;
using floatx4 = __attribute__((ext_vector_type(4))) float;

__device__ __forceinline__ float bf2f(unsigned short u) {
  return __uint_as_float(((unsigned int)u) << 16);
}
__device__ __forceinline__ unsigned short f2bf(float f) {
  unsigned int u = __float_as_uint(f);
  u += 0x7fffu + ((u >> 16) & 1u);   // round-to-nearest-even
  return (unsigned short)(u >> 16);
}
// async global->LDS, 16 bytes per lane. LDS dest must be wave-uniform base + lane*16.
__device__ __forceinline__ void gl_lds16(const void* g, void* l) {
  __builtin_amdgcn_global_load_lds(
      (__attribute__((address_space(1))) void*)g,
      (__attribute__((address_space(3))) void*)l, 16, 0, 0);
}

// ---------------- weight transpose + bf16 convert: Out[f][d] = W[d][f] ----------------
__global__ __launch_bounds__(256) void transpose_w(
    const float* __restrict__ Wq, const float* __restrict__ Wk,
    const float* __restrict__ Wv, const float* __restrict__ Wo,
    unsigned short* __restrict__ wqkvt, unsigned short* __restrict__ wot)
{
  __shared__ float tile[32][33];
  const float* W; unsigned short* Out;
  int z = blockIdx.z;
  if      (z == 0) { W = Wq; Out = wqkvt; }
  else if (z == 1) { W = Wk; Out = wqkvt + (size_t)DD * DD; }
  else if (z == 2) { W = Wv; Out = wqkvt + 2 * (size_t)DD * DD; }
  else             { W = Wo; Out = wot; }
  int tx = threadIdx.x, ty = threadIdx.y;
  int d0 = blockIdx.y * 32, f0 = blockIdx.x * 32;
#pragma unroll
  for (int i = 0; i < 4; i++)
    tile[ty + i * 8][tx] = W[(size_t)(d0 + ty + i * 8) * DD + f0 + tx];
  __syncthreads();
#pragma unroll
  for (int i = 0; i < 4; i++)
    Out[(size_t)(f0 + ty + i * 8) * DD + d0 + tx] = f2bf(tile[tx][ty + i * 8]);
}

// ---------------- x -> bf16 ----------------
__global__ __launch_bounds__(256) void conv_x(const float* __restrict__ x,
                                              unsigned short* __restrict__ xb)
{
  size_t i = ((size_t)blockIdx.x * 256 + threadIdx.x) * 4;
  float4 v = *(const float4*)(x + i);
  ushort4 o;
  o.x = f2bf(v.x); o.y = f2bf(v.y); o.z = f2bf(v.z); o.w = f2bf(v.w);
  *(ushort4*)(xb + i) = o;
}

// ---------------- bf16 MFMA GEMM, B^T layout (m97 recipe) ----------------
// C[M,N] = A[M,K] * Bt[N,K]^T (+bias). 128x128 tile, BK=32, 256 threads.
template <bool OUTF32>
__global__ __launch_bounds__(256) void gemm_bt(
    const unsigned short* __restrict__ A, const unsigned short* __restrict__ Bt,
    const float* __restrict__ bias, void* __restrict__ Cout,
    int M, int N, int K)
{
  __shared__ unsigned short As[128 * 32];
  __shared__ unsigned short Bs[128 * 32];
  int t = threadIdx.x;
  int m0 = blockIdx.y * 128, n0 = blockIdx.x * 128;
  int w = t >> 6, lane = t & 63, qd = lane >> 4, l16 = lane & 15;
  int wm = (w >> 1) * 64, wn = (w & 1) * 64;
  floatx4 zero4 = {0.f, 0.f, 0.f, 0.f};
  floatx4 acc[4][4];
#pragma unroll
  for (int i = 0; i < 4; i++)
#pragma unroll
    for (int j = 0; j < 4; j++) acc[i][j] = zero4;

  const unsigned short* Ab = A  + (size_t)(m0 + (t >> 2)) * K + (t & 3) * 8;
  const unsigned short* Bb = Bt + (size_t)(n0 + (t >> 2)) * K + (t & 3) * 8;
  size_t half = (size_t)64 * K;

  for (int k0 = 0; k0 < K; k0 += 32) {
    __syncthreads();
    gl_lds16(Ab + k0,        &As[t * 8]);
    gl_lds16(Ab + half + k0, &As[2048 + t * 8]);
    gl_lds16(Bb + k0,        &Bs[t * 8]);
    gl_lds16(Bb + half + k0, &Bs[2048 + t * 8]);
    __syncthreads();
    short8 af[4], bfr[4];
#pragma unroll
    for (int i = 0; i < 4; i++)
      af[i] = *(const short8*)&As[(wm + i * 16 + l16) * 32 + qd * 8];
#pragma unroll
    for (int j = 0; j < 4; j++)
      bfr[j] = *(const short8*)&Bs[(wn + j * 16 + l16) * 32 + qd * 8];
#pragma unroll
    for (int i = 0; i < 4; i++)
#pragma unroll
      for (int j = 0; j < 4; j++)
        acc[i][j] = __builtin_amdgcn_mfma_f32_16x16x32_bf16(af[i], bfr[j], acc[i][j], 0, 0, 0);
  }

#pragma unroll
  for (int i = 0; i < 4; i++)
#pragma unroll
    for (int j = 0; j < 4; j++) {
      int row = m0 + wm + i * 16 + qd * 4;
      int col = n0 + wn + j * 16 + l16;
      float bsv = bias ? bias[col] : 0.f;
#pragma unroll
      for (int r = 0; r < 4; r++) {
        float v = acc[i][j][r] + bsv;
        if (OUTF32) ((float*)Cout)[(size_t)(row + r) * N + col] = v;
        else ((unsigned short*)Cout)[(size_t)(row + r) * N + col] = f2bf(v);
      }
    }
}

// ---------------- RoPE + bias + rearrange q,k: qkv[BS,3D] -> [B,H,S,HD] ----------------
// q is pre-scaled by 1/sqrt(HD) so attention skips the scale multiply.
__global__ __launch_bounds__(256) void rope_qk(
    const unsigned short* __restrict__ qkv, const float* __restrict__ bq,
    const float* __restrict__ bk, unsigned short* __restrict__ q_r,
    unsigned short* __restrict__ k_r)
{
  int lin = blockIdx.x * 256 + threadIdx.x;
  int i = lin & 63;
  int s = (lin >> 6) & (SS - 1);
  int h = (lin >> 17) & (HH - 1);
  int b = lin >> 21;
  size_t row = (size_t)(b * SS + s) * (3 * DD);
  int f = h * HDD + i;
  float q1 = bf2f(qkv[row + f])            + bq[f];
  float q2 = bf2f(qkv[row + f + 64])       + bq[f + 64];
  float k1 = bf2f(qkv[row + DD + f])       + bk[f];
  float k2 = bf2f(qkv[row + DD + f + 64])  + bk[f + 64];
  float inv = powf(10000.f, -(float)i * (1.f / 64.f));
  float ang = (float)s * inv;
  float sn, c;
  sincosf(ang, &sn, &c);
  const float qs = 0.08838834764831845f;  // 1/sqrt(128)
  size_t ob = ((size_t)(b * HH + h) * SS + s) * HDD;
  q_r[ob + i]      = f2bf((q1 * c - q2 * sn) * qs);
  q_r[ob + i + 64] = f2bf((q1 * sn + q2 * c) * qs);
  k_r[ob + i]      = f2bf(k1 * c - k2 * sn);
  k_r[ob + i + 64] = f2bf(k1 * sn + k2 * c);
}

// ---------------- V transpose: qkv v-part -> v_t[B,H,HD,S] (+bias) ----------------
__global__ __launch_bounds__(256) void v_transpose(
    const unsigned short* __restrict__ qkv, const float* __restrict__ bv,
    unsigned short* __restrict__ v_t)
{
  __shared__ float tile[32][33];
  int bh = blockIdx.z; int b = bh >> 4, h = bh & 15;
  int s0 = blockIdx.x * 32, d0 = blockIdx.y * 32;
  int tx = threadIdx.x, ty = threadIdx.y;
#pragma unroll
  for (int i = 0; i < 4; i++) {
    int s = s0 + ty + i * 8, dh = d0 + tx;
    tile[ty + i * 8][tx] =
        bf2f(qkv[(size_t)(b * SS + s) * (3 * DD) + 2 * DD + h * HDD + dh]) + bv[h * HDD + dh];
  }
  __syncthreads();
#pragma unroll
  for (int i = 0; i < 4; i++)
    v_t[((size_t)(b * HH + h) * HDD + d0 + ty + i * 8) * SS + s0 + tx] =
        f2bf(tile[tx][ty + i * 8]);
}

// ---------------- flash attention v2 ----------------
// grid: (S/128, B*H). 256 threads = 4 waves; wave w owns q rows [w*32, w*32+32)
// as TWO 16-row m-tiles -> K/V LDS fragments are loaded once, used twice
// (register-level reuse halves LDS read bytes per q-row vs v1).
// LDS K/V/P tiles XOR-chunk-swizzled (16B chunks) to avoid bank conflicts.
__global__ __launch_bounds__(256, 2) void attn_kernel(
    const unsigned short* __restrict__ q_r, const unsigned short* __restrict__ k_r,
    const unsigned short* __restrict__ v_t, unsigned short* __restrict__ aout)
{
  __shared__ unsigned short Ks[64 * 128];   // [key][hd], swizzled chunks
  __shared__ unsigned short Vs[128 * 64];   // [hd][key], swizzled chunks
  __shared__ unsigned short Ps[4][32 * 64]; // per-wave P [qrow 0..31][key], swizzled
  int t = threadIdx.x, w = t >> 6, lane = t & 63, qd = lane >> 4, l16 = lane & 15;
  int bh = blockIdx.y, q0 = blockIdx.x * 128;
  const unsigned short* qb = q_r + (size_t)bh * SS * HDD;
  const unsigned short* kb = k_r + (size_t)bh * SS * HDD;
  const unsigned short* vb = v_t + (size_t)bh * HDD * SS;

  // persistent Q fragments: 2 m-tiles x 4 k-steps
  short8 aq[2][4];
#pragma unroll
  for (int mi = 0; mi < 2; mi++)
#pragma unroll
    for (int ks = 0; ks < 4; ks++)
      aq[mi][ks] = *(const short8*)
          &qb[(size_t)(q0 + w * 32 + mi * 16 + l16) * HDD + ks * 32 + qd * 8];

  float m_i[2][4], l_i[2][4];
  floatx4 zero4 = {0.f, 0.f, 0.f, 0.f};
  floatx4 o[2][8];
#pragma unroll
  for (int mi = 0; mi < 2; mi++)
#pragma unroll
    for (int r = 0; r < 4; r++) { m_i[mi][r] = -1e30f; l_i[mi][r] = 0.f; }
#pragma unroll
  for (int mi = 0; mi < 2; mi++)
#pragma unroll
    for (int n = 0; n < 8; n++) o[mi][n] = zero4;

  for (int kt = 0; kt < SS; kt += 64) {
    __syncthreads();
#pragma unroll
    for (int c = 0; c < 4; c++) {       // stage K tile: 64 rows x 128 elems
      int flat = c * 256 + t;
      int r = flat >> 4, cc = flat & 15;
      gl_lds16(kb + (size_t)(kt + r) * HDD + (cc ^ (r & 15)) * 8, &Ks[flat * 8]);
    }
#pragma unroll
    for (int c = 0; c < 4; c++) {       // stage V^T tile: 128 rows x 64 elems
      int flat = c * 256 + t;
      int r = flat >> 3, cc = flat & 7;
      gl_lds16(vb + (size_t)r * SS + kt + (cc ^ (r & 7)) * 8, &Vs[flat * 8]);
    }
    __syncthreads();

    // ---- QK^T: scores for 32 q-rows x 64 keys (q pre-scaled by 1/sqrt(HD))
    floatx4 sc[2][4];
#pragma unroll
    for (int mi = 0; mi < 2; mi++)
#pragma unroll
      for (int j = 0; j < 4; j++) sc[mi][j] = zero4;
#pragma unroll
    for (int j = 0; j < 4; j++) {
      int krow = j * 16 + l16;
#pragma unroll
      for (int ks = 0; ks < 4; ks++) {
        int chunk = ks * 4 + qd;
        short8 bk8 = *(const short8*)&Ks[krow * 128 + ((chunk ^ (krow & 15)) * 8)];
        sc[0][j] = __builtin_amdgcn_mfma_f32_16x16x32_bf16(aq[0][ks], bk8, sc[0][j], 0, 0, 0);
        sc[1][j] = __builtin_amdgcn_mfma_f32_16x16x32_bf16(aq[1][ks], bk8, sc[1][j], 0, 0, 0);
      }
    }

    // ---- online softmax
    float rmax[2][4];
#pragma unroll
    for (int mi = 0; mi < 2; mi++)
#pragma unroll
      for (int r = 0; r < 4; r++) rmax[mi][r] = -1e30f;
#pragma unroll
    for (int mi = 0; mi < 2; mi++)
#pragma unroll
      for (int j = 0; j < 4; j++)
#pragma unroll
        for (int r = 0; r < 4; r++)
          rmax[mi][r] = fmaxf(rmax[mi][r], sc[mi][j][r]);
#pragma unroll
    for (int mask = 1; mask < 16; mask <<= 1)
#pragma unroll
      for (int mi = 0; mi < 2; mi++)
#pragma unroll
        for (int r = 0; r < 4; r++)
          rmax[mi][r] = fmaxf(rmax[mi][r], __shfl_xor(rmax[mi][r], mask, 64));

    // rescale only if some row's max increased (ballot-guarded, wave-uniform)
    bool up = false;
#pragma unroll
    for (int mi = 0; mi < 2; mi++)
#pragma unroll
      for (int r = 0; r < 4; r++) up = up || (rmax[mi][r] > m_i[mi][r]);
    if (__ballot(up) != 0ull) {
#pragma unroll
      for (int mi = 0; mi < 2; mi++)
#pragma unroll
        for (int r = 0; r < 4; r++) {
          float mn = fmaxf(m_i[mi][r], rmax[mi][r]);
          float a = __expf(m_i[mi][r] - mn);
          m_i[mi][r] = mn;
          l_i[mi][r] *= a;
#pragma unroll
          for (int n = 0; n < 8; n++) o[mi][n][r] *= a;
        }
    }

    float rsum[2][4];
#pragma unroll
    for (int mi = 0; mi < 2; mi++)
#pragma unroll
      for (int r = 0; r < 4; r++) rsum[mi][r] = 0.f;
#pragma unroll
    for (int mi = 0; mi < 2; mi++)
#pragma unroll
      for (int j = 0; j < 4; j++)
#pragma unroll
        for (int r = 0; r < 4; r++) {
          float p = __expf(sc[mi][j][r] - m_i[mi][r]);
          rsum[mi][r] += p;
          int prow = mi * 16 + qd * 4 + r, pcol = j * 16 + l16;
          int chunk = pcol >> 3;
          Ps[w][prow * 64 + ((chunk ^ (prow & 7)) * 8) + (pcol & 7)] = f2bf(p);
        }
#pragma unroll
    for (int mask = 1; mask < 16; mask <<= 1)
#pragma unroll
      for (int mi = 0; mi < 2; mi++)
#pragma unroll
        for (int r = 0; r < 4; r++) rsum[mi][r] += __shfl_xor(rsum[mi][r], mask, 64);
#pragma unroll
    for (int mi = 0; mi < 2; mi++)
#pragma unroll
      for (int r = 0; r < 4; r++) l_i[mi][r] += rsum[mi][r];

    // ---- PV: O += P * V^T^T  (V frags loaded once, used for both m-tiles)
    short8 ap[2][2];
#pragma unroll
    for (int mi = 0; mi < 2; mi++)
#pragma unroll
      for (int ks = 0; ks < 2; ks++) {
        int prow = mi * 16 + l16;
        int chunk = ks * 4 + qd;
        ap[mi][ks] = *(const short8*)&Ps[w][prow * 64 + ((chunk ^ (prow & 7)) * 8)];
      }
#pragma unroll
    for (int n = 0; n < 8; n++) {
      int vrow = n * 16 + l16;
#pragma unroll
      for (int ks = 0; ks < 2; ks++) {
        int chunk = ks * 4 + qd;
        short8 bv8 = *(const short8*)&Vs[vrow * 64 + ((chunk ^ (vrow & 7)) * 8)];
        o[0][n] = __builtin_amdgcn_mfma_f32_16x16x32_bf16(ap[0][ks], bv8, o[0][n], 0, 0, 0);
        o[1][n] = __builtin_amdgcn_mfma_f32_16x16x32_bf16(ap[1][ks], bv8, o[1][n], 0, 0, 0);
      }
    }
  }

  int b = bh >> 4, h = bh & 15;
#pragma unroll
  for (int mi = 0; mi < 2; mi++)
#pragma unroll
    for (int r = 0; r < 4; r++) {
      int srow = q0 + w * 32 + mi * 16 + qd * 4 + r;
      float inv_l = 1.f / l_i[mi][r];
      size_t base = ((size_t)(b * SS + srow)) * DD + h * HDD;
#pragma unroll
      for (int n = 0; n < 8; n++)
        aout[base + n * 16 + l16] = f2bf(o[mi][n][r] * inv_l);
    }
}

// ---------------- launch ----------------
extern "C" void kernel_launch(void* const* d_in, const int* in_sizes, int n_in,
                              void* d_out, int out_size, void* d_ws, size_t ws_size,
                              hipStream_t stream) {
  const float* x  = (const float*)d_in[0];
  const float* Wq = (const float*)d_in[1];
  const float* bq = (const float*)d_in[2];
  const float* Wk = (const float*)d_in[3];
  const float* bk = (const float*)d_in[4];
  const float* Wv = (const float*)d_in[5];
  const float* bv = (const float*)d_in[6];
  const float* Wo = (const float*)d_in[7];
  const float* bo = (const float*)d_in[8];
  float* out = (float*)d_out;

  char* ws = (char*)d_ws;
  // workspace layout (bytes); attn_out aliases xb (xb dead after QKV GEMM)
  unsigned short* xb      = (unsigned short*)(ws + 0);            // [BS,D] bf16, 16 MB
  unsigned short* wqkvt   = (unsigned short*)(ws + 16777216);     // [3D,D] bf16, 24 MB
  unsigned short* wot     = (unsigned short*)(ws + 41943040);     // [D,D]  bf16, 8 MB
  unsigned short* qkv     = (unsigned short*)(ws + 50331648);     // [BS,3D] bf16, 48 MB
  unsigned short* q_r     = (unsigned short*)(ws + 100663296);    // [B,H,S,HD] 16 MB
  unsigned short* k_r     = (unsigned short*)(ws + 117440512);    // [B,H,S,HD] 16 MB
  unsigned short* v_t     = (unsigned short*)(ws + 134217728);    // [B,H,HD,S] 16 MB
  unsigned short* attn_o  = xb;                                   // alias

  transpose_w<<<dim3(DD / 32, DD / 32, 4), dim3(32, 8), 0, stream>>>(
      Wq, Wk, Wv, Wo, wqkvt, wot);
  conv_x<<<dim3((BSR * DD) / 1024), dim3(256), 0, stream>>>(x, xb);
  gemm_bt<false><<<dim3(3 * DD / 128, BSR / 128), dim3(256), 0, stream>>>(
      xb, wqkvt, nullptr, qkv, BSR, 3 * DD, DD);
  rope_qk<<<dim3((BB * HH * SS * 64) / 256), dim3(256), 0, stream>>>(
      qkv, bq, bk, q_r, k_r);
  v_transpose<<<dim3(SS / 32, HDD / 32, BB * HH), dim3(32, 8), 0, stream>>>(
      qkv, bv, v_t);
  attn_kernel<<<dim3(SS / 128, BB * HH), dim3(256), 0, stream>>>(
      q_r, k_r, v_t, attn_o);
  gemm_bt<true><<<dim3(DD / 128, BSR / 128), dim3(256), 0, stream>>>(
      attn_o, wot, bo, out, BSR, DD, DD);
}

// Round 3
// 459.343 us; speedup vs baseline: 1.2050x; 1.0896x over previous
//
#include <hip/hip_runtime.h>

// Problem constants
#define BB  2
#define SS  2048
#define DD  2048
#define HH  16
#define HDD 128
#define BSR 4096   // BB*SS rows

using short8  = __attribute__((ext_vector_type(8))) short;
using floatx4 = __attribute__((ext_vector_type(4))) float;

__device__ __forceinline__ float bf2f(unsigned short u) {
  return __uint_as_float(((unsigned int)u) << 16);
}
__device__ __forceinline__ unsigned short f2bf(float f) {
  unsigned int u = __float_as_uint(f);
  u += 0x7fffu + ((u >> 16) & 1u);   // round-to-nearest-even
  return (unsigned short)(u >> 16);
}
// pack two floats -> two bf16 (rne) in one u32 (a=low, b=high)
__device__ __forceinline__ unsigned int pk2bf(float a, float b) {
  unsigned int ua = __float_as_uint(a);
  ua += 0x7fffu + ((ua >> 16) & 1u);
  unsigned int ub = __float_as_uint(b);
  ub += 0x7fffu + ((ub >> 16) & 1u);
  return (ua >> 16) | (ub & 0xffff0000u);
}
// async global->LDS, 16 bytes per lane. LDS dest must be wave-uniform base + lane*16.
__device__ __forceinline__ void gl_lds16(const void* g, void* l) {
  __builtin_amdgcn_global_load_lds(
      (__attribute__((address_space(1))) void*)g,
      (__attribute__((address_space(3))) void*)l, 16, 0, 0);
}

// ---------------- weight transpose + bf16 convert: Out[f][d] = W[d][f] ----------------
__global__ __launch_bounds__(256) void transpose_w(
    const float* __restrict__ Wq, const float* __restrict__ Wk,
    const float* __restrict__ Wv, const float* __restrict__ Wo,
    unsigned short* __restrict__ wqkvt, unsigned short* __restrict__ wot)
{
  __shared__ float tile[32][33];
  const float* W; unsigned short* Out;
  int z = blockIdx.z;
  if      (z == 0) { W = Wq; Out = wqkvt; }
  else if (z == 1) { W = Wk; Out = wqkvt + (size_t)DD * DD; }
  else if (z == 2) { W = Wv; Out = wqkvt + 2 * (size_t)DD * DD; }
  else             { W = Wo; Out = wot; }
  int tx = threadIdx.x, ty = threadIdx.y;
  int d0 = blockIdx.y * 32, f0 = blockIdx.x * 32;
#pragma unroll
  for (int i = 0; i < 4; i++)
    tile[ty + i * 8][tx] = W[(size_t)(d0 + ty + i * 8) * DD + f0 + tx];
  __syncthreads();
#pragma unroll
  for (int i = 0; i < 4; i++)
    Out[(size_t)(f0 + ty + i * 8) * DD + d0 + tx] = f2bf(tile[tx][ty + i * 8]);
}

// ---------------- x -> bf16 ----------------
__global__ __launch_bounds__(256) void conv_x(const float* __restrict__ x,
                                              unsigned short* __restrict__ xb)
{
  size_t i = ((size_t)blockIdx.x * 256 + threadIdx.x) * 4;
  float4 v = *(const float4*)(x + i);
  ushort4 o;
  o.x = f2bf(v.x); o.y = f2bf(v.y); o.z = f2bf(v.z); o.w = f2bf(v.w);
  *(ushort4*)(xb + i) = o;
}

// ---------------- bf16 MFMA GEMM, B^T layout (m97 recipe + bank-conflict swizzle) -----
// C[M,N] = A[M,K] * Bt[N,K]^T (+bias). 128x128 tile, BK=32, 256 threads.
// LDS (row, cc) holds global chunk cc ^ ((row>>1)&3): spreads frag-read lanes
// over 8 bank groups (2-way = free) instead of 2 (8-way conflict).
template <bool OUTF32>
__global__ __launch_bounds__(256) void gemm_bt(
    const unsigned short* __restrict__ A, const unsigned short* __restrict__ Bt,
    const float* __restrict__ bias, void* __restrict__ Cout,
    int M, int N, int K)
{
  __shared__ unsigned short As[128 * 32];
  __shared__ unsigned short Bs[128 * 32];
  int t = threadIdx.x;
  int m0 = blockIdx.y * 128, n0 = blockIdx.x * 128;
  int w = t >> 6, lane = t & 63, qd = lane >> 4, l16 = lane & 15;
  int wm = (w >> 1) * 64, wn = (w & 1) * 64;
  floatx4 zero4 = {0.f, 0.f, 0.f, 0.f};
  floatx4 acc[4][4];
#pragma unroll
  for (int i = 0; i < 4; i++)
#pragma unroll
    for (int j = 0; j < 4; j++) acc[i][j] = zero4;

  // staging: row = t>>2, LDS chunk = t&3, global chunk = (t&3) ^ ((t>>3)&3)
  int gchunk = (t & 3) ^ ((t >> 3) & 3);
  const unsigned short* Ab = A  + (size_t)(m0 + (t >> 2)) * K + gchunk * 8;
  const unsigned short* Bb = Bt + (size_t)(n0 + (t >> 2)) * K + gchunk * 8;
  size_t half = (size_t)64 * K;
  // frag read chunk: qd ^ ((row>>1)&3), row = wm+i*16+l16 -> ((l16>>1)&3)
  int cswz = (qd ^ ((l16 >> 1) & 3)) * 8;

  for (int k0 = 0; k0 < K; k0 += 32) {
    __syncthreads();
    gl_lds16(Ab + k0,        &As[t * 8]);
    gl_lds16(Ab + half + k0, &As[2048 + t * 8]);
    gl_lds16(Bb + k0,        &Bs[t * 8]);
    gl_lds16(Bb + half + k0, &Bs[2048 + t * 8]);
    __syncthreads();
    short8 af[4], bfr[4];
#pragma unroll
    for (int i = 0; i < 4; i++)
      af[i] = *(const short8*)&As[(wm + i * 16 + l16) * 32 + cswz];
#pragma unroll
    for (int j = 0; j < 4; j++)
      bfr[j] = *(const short8*)&Bs[(wn + j * 16 + l16) * 32 + cswz];
#pragma unroll
    for (int i = 0; i < 4; i++)
#pragma unroll
      for (int j = 0; j < 4; j++)
        acc[i][j] = __builtin_amdgcn_mfma_f32_16x16x32_bf16(af[i], bfr[j], acc[i][j], 0, 0, 0);
  }

#pragma unroll
  for (int i = 0; i < 4; i++)
#pragma unroll
    for (int j = 0; j < 4; j++) {
      int row = m0 + wm + i * 16 + qd * 4;
      int col = n0 + wn + j * 16 + l16;
      float bsv = bias ? bias[col] : 0.f;
#pragma unroll
      for (int r = 0; r < 4; r++) {
        float v = acc[i][j][r] + bsv;
        if (OUTF32) ((float*)Cout)[(size_t)(row + r) * N + col] = v;
        else ((unsigned short*)Cout)[(size_t)(row + r) * N + col] = f2bf(v);
      }
    }
}

// ---------------- RoPE + bias + rearrange q,k: qkv[BS,3D] -> [B,H,S,HD] ----------------
// q is pre-scaled by 1/sqrt(HD) so attention skips the scale multiply.
__global__ __launch_bounds__(256) void rope_qk(
    const unsigned short* __restrict__ qkv, const float* __restrict__ bq,
    const float* __restrict__ bk, unsigned short* __restrict__ q_r,
    unsigned short* __restrict__ k_r)
{
  int lin = blockIdx.x * 256 + threadIdx.x;
  int i = lin & 63;
  int s = (lin >> 6) & (SS - 1);
  int h = (lin >> 17) & (HH - 1);
  int b = lin >> 21;
  size_t row = (size_t)(b * SS + s) * (3 * DD);
  int f = h * HDD + i;
  float q1 = bf2f(qkv[row + f])            + bq[f];
  float q2 = bf2f(qkv[row + f + 64])       + bq[f + 64];
  float k1 = bf2f(qkv[row + DD + f])       + bk[f];
  float k2 = bf2f(qkv[row + DD + f + 64])  + bk[f + 64];
  float inv = powf(10000.f, -(float)i * (1.f / 64.f));
  float ang = (float)s * inv;
  float sn, c;
  sincosf(ang, &sn, &c);
  const float qs = 0.08838834764831845f;  // 1/sqrt(128)
  size_t ob = ((size_t)(b * HH + h) * SS + s) * HDD;
  q_r[ob + i]      = f2bf((q1 * c - q2 * sn) * qs);
  q_r[ob + i + 64] = f2bf((q1 * sn + q2 * c) * qs);
  k_r[ob + i]      = f2bf(k1 * c - k2 * sn);
  k_r[ob + i + 64] = f2bf(k1 * sn + k2 * c);
}

// ---------------- V transpose: qkv v-part -> v_t[B,H,HD,S'] (+bias) ----------------
// Key order is PERMUTED within each 64-key tile so the attention PV B-fragment
// (assembled in registers from softmax output) sees keys in MFMA k-slot order:
// slot kappa = ks*32+qd*8+j holds key y with qd=(y>>2)&3, r=y&3, jj=y>>4,
// ks=jj>>1, j=(jj&1)*4+r  =>  kappa(y) = ((y>>5)&1)*32+((y>>2)&3)*8+((y>>4)&1)*4+(y&3)
__global__ __launch_bounds__(256) void v_transpose(
    const unsigned short* __restrict__ qkv, const float* __restrict__ bv,
    unsigned short* __restrict__ v_t)
{
  __shared__ float tile[32][33];
  int bh = blockIdx.z; int b = bh >> 4, h = bh & 15;
  int s0 = blockIdx.x * 32, d0 = blockIdx.y * 32;
  int tx = threadIdx.x, ty = threadIdx.y;
#pragma unroll
  for (int i = 0; i < 4; i++) {
    int s = s0 + ty + i * 8, dh = d0 + tx;
    tile[ty + i * 8][tx] =
        bf2f(qkv[(size_t)(b * SS + s) * (3 * DD) + 2 * DD + h * HDD + dh]) + bv[h * HDD + dh];
  }
  __syncthreads();
  // permuted column for this thread's store
  int s = s0 + tx;
  int y = s & 63;
  int kap = ((y >> 5) & 1) * 32 + ((y >> 2) & 3) * 8 + ((y >> 4) & 1) * 4 + (y & 3);
  int scol = (s & ~63) + kap;
#pragma unroll
  for (int i = 0; i < 4; i++)
    v_t[((size_t)(b * HH + h) * HDD + d0 + ty + i * 8) * SS + scol] =
        f2bf(tile[tx][ty + i * 8]);
}

// ---------------- flash attention v3 ----------------
// grid: (S/128, B*H). 256 threads = 4 waves; wave w owns q rows [w*32, w*32+32).
// Computes S^T = K.Q^T so the MFMA C-layout puts each q-row's scores in ONE
// lane-group (col = lane&15 = qrow): softmax reductions are per-lane + 2
// shuffles (xor 16,32). PV is O^T = V^T.P^T with the P^T B-fragment built
// directly in registers (packed bf16 pairs) -- no P LDS round-trip. V's key
// order is pre-permuted by v_transpose to match B-fragment k-slot order.
__global__ __launch_bounds__(256, 2) void attn_kernel(
    const unsigned short* __restrict__ q_r, const unsigned short* __restrict__ k_r,
    const unsigned short* __restrict__ v_t, unsigned short* __restrict__ aout)
{
  __shared__ unsigned short Ks[64 * 128];   // [key][hd], swizzled chunks
  __shared__ unsigned short Vs[128 * 64];   // [hd][key-slot], swizzled chunks
  int t = threadIdx.x, w = t >> 6, lane = t & 63, qd = lane >> 4, l16 = lane & 15;
  int bh = blockIdx.y, q0 = blockIdx.x * 128;
  const unsigned short* qb = q_r + (size_t)bh * SS * HDD;
  const unsigned short* kb = k_r + (size_t)bh * SS * HDD;
  const unsigned short* vb = v_t + (size_t)bh * HDD * SS;

  // persistent Q fragments (B-operand: lane l16 = qrow): 2 n-tiles x 4 k-steps
  short8 aq[2][4];
#pragma unroll
  for (int mi = 0; mi < 2; mi++)
#pragma unroll
    for (int ks = 0; ks < 4; ks++)
      aq[mi][ks] = *(const short8*)
          &qb[(size_t)(q0 + w * 32 + mi * 16 + l16) * HDD + ks * 32 + qd * 8];

  float m_i[2], l_i[2];
  floatx4 zero4 = {0.f, 0.f, 0.f, 0.f};
  floatx4 o[2][8];   // O^T: rows hd (8 blocks of 16), cols qrow (mi)
#pragma unroll
  for (int mi = 0; mi < 2; mi++) { m_i[mi] = -1e30f; l_i[mi] = 0.f; }
#pragma unroll
  for (int mi = 0; mi < 2; mi++)
#pragma unroll
    for (int n = 0; n < 8; n++) o[mi][n] = zero4;

  for (int kt = 0; kt < SS; kt += 64) {
    __syncthreads();
#pragma unroll
    for (int c = 0; c < 4; c++) {       // stage K tile: 64 rows x 128 elems
      int flat = c * 256 + t;
      int r = flat >> 4, cc = flat & 15;
      gl_lds16(kb + (size_t)(kt + r) * HDD + (cc ^ (r & 15)) * 8, &Ks[flat * 8]);
    }
#pragma unroll
    for (int c = 0; c < 4; c++) {       // stage V^T tile: 128 rows x 64 slots
      int flat = c * 256 + t;
      int r = flat >> 3, cc = flat & 7;
      gl_lds16(vb + (size_t)r * SS + kt + (cc ^ (r & 7)) * 8, &Vs[flat * 8]);
    }
    __syncthreads();

    // ---- S^T = K.Q^T: rows = keys (4 j-blocks), cols = qrows (2 mi-blocks)
    floatx4 sc[2][4];
#pragma unroll
    for (int mi = 0; mi < 2; mi++)
#pragma unroll
      for (int j = 0; j < 4; j++) sc[mi][j] = zero4;
#pragma unroll
    for (int j = 0; j < 4; j++) {
      int krow = j * 16 + l16;
#pragma unroll
      for (int ks = 0; ks < 4; ks++) {
        int chunk = ks * 4 + qd;
        short8 kf = *(const short8*)&Ks[krow * 128 + ((chunk ^ (krow & 15)) * 8)];
        sc[0][j] = __builtin_amdgcn_mfma_f32_16x16x32_bf16(kf, aq[0][ks], sc[0][j], 0, 0, 0);
        sc[1][j] = __builtin_amdgcn_mfma_f32_16x16x32_bf16(kf, aq[1][ks], sc[1][j], 0, 0, 0);
      }
    }
    // per lane: sc[mi][j][r] = S[qrow = q0+w*32+mi*16+l16][key = kt+16j+4qd+r]

    // ---- online softmax (per-lane 16-val reduce + xor16/xor32 shuffles)
    float rmax[2];
#pragma unroll
    for (int mi = 0; mi < 2; mi++) {
      float m = sc[mi][0][0];
#pragma unroll
      for (int j = 0; j < 4; j++)
#pragma unroll
        for (int r = 0; r < 4; r++) m = fmaxf(m, sc[mi][j][r]);
      m = fmaxf(m, __shfl_xor(m, 16, 64));
      m = fmaxf(m, __shfl_xor(m, 32, 64));
      rmax[mi] = m;
    }

    bool up = (rmax[0] > m_i[0]) || (rmax[1] > m_i[1]);
    if (__ballot(up) != 0ull) {
#pragma unroll
      for (int mi = 0; mi < 2; mi++) {
        float mn = fmaxf(m_i[mi], rmax[mi]);
        float a = __expf(m_i[mi] - mn);
        m_i[mi] = mn;
        l_i[mi] *= a;
#pragma unroll
        for (int n = 0; n < 8; n++)
#pragma unroll
          for (int r = 0; r < 4; r++) o[mi][n][r] *= a;
      }
    }

    // exp + pack bf16 pairs (adjacent keys r,r+1) -> P^T B-frag registers
    unsigned int pr[2][4][2];
#pragma unroll
    for (int mi = 0; mi < 2; mi++) {
      float s0 = 0.f;
#pragma unroll
      for (int j = 0; j < 4; j++) {
        float p0 = __expf(sc[mi][j][0] - m_i[mi]);
        float p1 = __expf(sc[mi][j][1] - m_i[mi]);
        float p2 = __expf(sc[mi][j][2] - m_i[mi]);
        float p3 = __expf(sc[mi][j][3] - m_i[mi]);
        s0 += (p0 + p1) + (p2 + p3);
        pr[mi][j][0] = pk2bf(p0, p1);
        pr[mi][j][1] = pk2bf(p2, p3);
      }
      s0 += __shfl_xor(s0, 16, 64);
      s0 += __shfl_xor(s0, 32, 64);
      l_i[mi] += s0;
    }

    // ---- PV: O^T += V^T . P^T  (B-frag = pr registers, key order matches V perm)
#pragma unroll
    for (int n = 0; n < 8; n++) {
      int vrow = n * 16 + l16;
#pragma unroll
      for (int ks = 0; ks < 2; ks++) {
        int chunk = ks * 4 + qd;
        short8 av = *(const short8*)&Vs[vrow * 64 + ((chunk ^ (vrow & 7)) * 8)];
        union { unsigned int u[4]; short8 v; } bp0, bp1;
        bp0.u[0] = pr[0][2 * ks][0];     bp0.u[1] = pr[0][2 * ks][1];
        bp0.u[2] = pr[0][2 * ks + 1][0]; bp0.u[3] = pr[0][2 * ks + 1][1];
        bp1.u[0] = pr[1][2 * ks][0];     bp1.u[1] = pr[1][2 * ks][1];
        bp1.u[2] = pr[1][2 * ks + 1][0]; bp1.u[3] = pr[1][2 * ks + 1][1];
        o[0][n] = __builtin_amdgcn_mfma_f32_16x16x32_bf16(av, bp0.v, o[0][n], 0, 0, 0);
        o[1][n] = __builtin_amdgcn_mfma_f32_16x16x32_bf16(av, bp1.v, o[1][n], 0, 0, 0);
      }
    }
  }

  // epilogue: O^T cols -> aout rows; pack 4 bf16 (contiguous hd) per store
  int b = bh >> 4, h = bh & 15;
#pragma unroll
  for (int mi = 0; mi < 2; mi++) {
    int qrow = q0 + w * 32 + mi * 16 + l16;
    float inv_l = 1.f / l_i[mi];
    size_t base = ((size_t)(b * SS + qrow)) * DD + h * HDD;
#pragma unroll
    for (int n = 0; n < 8; n++) {
      uint2 pkd;
      pkd.x = pk2bf(o[mi][n][0] * inv_l, o[mi][n][1] * inv_l);
      pkd.y = pk2bf(o[mi][n][2] * inv_l, o[mi][n][3] * inv_l);
      *(uint2*)&aout[base + n * 16 + qd * 4] = pkd;
    }
  }
}

// ---------------- launch ----------------
extern "C" void kernel_launch(void* const* d_in, const int* in_sizes, int n_in,
                              void* d_out, int out_size, void* d_ws, size_t ws_size,
                              hipStream_t stream) {
  const float* x  = (const float*)d_in[0];
  const float* Wq = (const float*)d_in[1];
  const float* bq = (const float*)d_in[2];
  const float* Wk = (const float*)d_in[3];
  const float* bk = (const float*)d_in[4];
  const float* Wv = (const float*)d_in[5];
  const float* bv = (const float*)d_in[6];
  const float* Wo = (const float*)d_in[7];
  const float* bo = (const float*)d_in[8];
  float* out = (float*)d_out;

  char* ws = (char*)d_ws;
  // workspace layout (bytes); attn_out aliases xb (xb dead after QKV GEMM)
  unsigned short* xb      = (unsigned short*)(ws + 0);            // [BS,D] bf16, 16 MB
  unsigned short* wqkvt   = (unsigned short*)(ws + 16777216);     // [3D,D] bf16, 24 MB
  unsigned short* wot     = (unsigned short*)(ws + 41943040);     // [D,D]  bf16, 8 MB
  unsigned short* qkv     = (unsigned short*)(ws + 50331648);     // [BS,3D] bf16, 48 MB
  unsigned short* q_r     = (unsigned short*)(ws + 100663296);    // [B,H,S,HD] 16 MB
  unsigned short* k_r     = (unsigned short*)(ws + 117440512);    // [B,H,S,HD] 16 MB
  unsigned short* v_t     = (unsigned short*)(ws + 134217728);    // [B,H,HD,S] 16 MB
  unsigned short* attn_o  = xb;                                   // alias

  transpose_w<<<dim3(DD / 32, DD / 32, 4), dim3(32, 8), 0, stream>>>(
      Wq, Wk, Wv, Wo, wqkvt, wot);
  conv_x<<<dim3((BSR * DD) / 1024), dim3(256), 0, stream>>>(x, xb);
  gemm_bt<false><<<dim3(3 * DD / 128, BSR / 128), dim3(256), 0, stream>>>(
      xb, wqkvt, nullptr, qkv, BSR, 3 * DD, DD);
  rope_qk<<<dim3((BB * HH * SS * 64) / 256), dim3(256), 0, stream>>>(
      qkv, bq, bk, q_r, k_r);
  v_transpose<<<dim3(SS / 32, HDD / 32, BB * HH), dim3(32, 8), 0, stream>>>(
      qkv, bv, v_t);
  attn_kernel<<<dim3(SS / 128, BB * HH), dim3(256), 0, stream>>>(
      q_r, k_r, v_t, attn_o);
  gemm_bt<true><<<dim3(DD / 128, BSR / 128), dim3(256), 0, stream>>>(
      attn_o, wot, bo, out, BSR, DD, DD);
}

// Round 4
// 443.680 us; speedup vs baseline: 1.2475x; 1.0353x over previous
//
#include <hip/hip_runtime.h>

// Problem constants
#define BB  2
#define SS  2048
#define DD  2048
#define HH  16
#define HDD 128
#define BSR 4096   // BB*SS rows

using short8  = __attribute__((ext_vector_type(8))) short;
using floatx4 = __attribute__((ext_vector_type(4))) float;

__device__ __forceinline__ float bf2f(unsigned short u) {
  return __uint_as_float(((unsigned int)u) << 16);
}
__device__ __forceinline__ unsigned short f2bf(float f) {
  unsigned int u = __float_as_uint(f);
  u += 0x7fffu + ((u >> 16) & 1u);   // round-to-nearest-even
  return (unsigned short)(u >> 16);
}
// pack two floats -> two bf16 (rne) in one u32 (a=low, b=high)
__device__ __forceinline__ unsigned int pk2bf(float a, float b) {
  unsigned int ua = __float_as_uint(a);
  ua += 0x7fffu + ((ua >> 16) & 1u);
  unsigned int ub = __float_as_uint(b);
  ub += 0x7fffu + ((ub >> 16) & 1u);
  return (ua >> 16) | (ub & 0xffff0000u);
}
// async global->LDS, 16 bytes per lane. LDS dest must be wave-uniform base + lane*16.
__device__ __forceinline__ void gl_lds16(const void* g, void* l) {
  __builtin_amdgcn_global_load_lds(
      (__attribute__((address_space(1))) void*)g,
      (__attribute__((address_space(3))) void*)l, 16, 0, 0);
}

// ---------------- weight transpose + bf16 convert: Out[f][d] = W[d][f] ----------------
__global__ __launch_bounds__(256) void transpose_w(
    const float* __restrict__ Wq, const float* __restrict__ Wk,
    const float* __restrict__ Wv, const float* __restrict__ Wo,
    unsigned short* __restrict__ wqkvt, unsigned short* __restrict__ wot)
{
  __shared__ float tile[32][33];
  const float* W; unsigned short* Out;
  int z = blockIdx.z;
  if      (z == 0) { W = Wq; Out = wqkvt; }
  else if (z == 1) { W = Wk; Out = wqkvt + (size_t)DD * DD; }
  else if (z == 2) { W = Wv; Out = wqkvt + 2 * (size_t)DD * DD; }
  else             { W = Wo; Out = wot; }
  int tx = threadIdx.x, ty = threadIdx.y;
  int d0 = blockIdx.y * 32, f0 = blockIdx.x * 32;
#pragma unroll
  for (int i = 0; i < 4; i++)
    tile[ty + i * 8][tx] = W[(size_t)(d0 + ty + i * 8) * DD + f0 + tx];
  __syncthreads();
#pragma unroll
  for (int i = 0; i < 4; i++)
    Out[(size_t)(f0 + ty + i * 8) * DD + d0 + tx] = f2bf(tile[tx][ty + i * 8]);
}

// ---------------- x -> bf16 ----------------
__global__ __launch_bounds__(256) void conv_x(const float* __restrict__ x,
                                              unsigned short* __restrict__ xb)
{
  size_t i = ((size_t)blockIdx.x * 256 + threadIdx.x) * 4;
  float4 v = *(const float4*)(x + i);
  ushort4 o;
  o.x = f2bf(v.x); o.y = f2bf(v.y); o.z = f2bf(v.z); o.w = f2bf(v.w);
  *(ushort4*)(xb + i) = o;
}

// ---------------- bf16 MFMA GEMM, B^T layout, BK=64 ----------------
// C[M,N] = A[M,K] * Bt[N,K]^T (+bias). 128x128 tile, BK=64, 256 threads.
// BK=64 halves barrier count vs BK=32 (same staging/ds_read/MFMA totals);
// 32KB LDS keeps 4+ blocks/CU. Row stride 128B -> XOR-chunk swizzle
// cc ^ (row&7): frag-read lanes spread over 8 bank-quads (2-way = free).
template <bool OUTF32>
__global__ __launch_bounds__(256) void gemm_bt(
    const unsigned short* __restrict__ A, const unsigned short* __restrict__ Bt,
    const float* __restrict__ bias, void* __restrict__ Cout,
    int M, int N, int K)
{
  __shared__ unsigned short As[128 * 64];
  __shared__ unsigned short Bs[128 * 64];
  int t = threadIdx.x;
  int m0 = blockIdx.y * 128, n0 = blockIdx.x * 128;
  int w = t >> 6, lane = t & 63, qd = lane >> 4, l16 = lane & 15;
  int wm = (w >> 1) * 64, wn = (w & 1) * 64;
  floatx4 zero4 = {0.f, 0.f, 0.f, 0.f};
  floatx4 acc[4][4];
#pragma unroll
  for (int i = 0; i < 4; i++)
#pragma unroll
    for (int j = 0; j < 4; j++) acc[i][j] = zero4;

  // staging: c-th issue covers rows c*32 + (t>>3), LDS chunk t&7,
  // global chunk = (t&7) ^ ((t>>3)&7)  (XOR within 128B segment: stays coalesced)
  int gchunk = (t & 7) ^ ((t >> 3) & 7);
  const unsigned short* Ab = A  + (size_t)(m0 + (t >> 3)) * K + gchunk * 8;
  const unsigned short* Bb = Bt + (size_t)(n0 + (t >> 3)) * K + gchunk * 8;
  size_t qK = (size_t)32 * K;

  for (int k0 = 0; k0 < K; k0 += 64) {
    __syncthreads();
#pragma unroll
    for (int c = 0; c < 4; c++) {
      gl_lds16(Ab + c * qK + k0, &As[(c * 256 + t) * 8]);
      gl_lds16(Bb + c * qK + k0, &Bs[(c * 256 + t) * 8]);
    }
    __syncthreads();
#pragma unroll
    for (int ks = 0; ks < 2; ks++) {
      int ch = ((ks * 4 + qd) ^ (l16 & 7)) * 8;
      short8 af[4], bfr[4];
#pragma unroll
      for (int i = 0; i < 4; i++)
        af[i] = *(const short8*)&As[(wm + i * 16 + l16) * 64 + ch];
#pragma unroll
      for (int j = 0; j < 4; j++)
        bfr[j] = *(const short8*)&Bs[(wn + j * 16 + l16) * 64 + ch];
#pragma unroll
      for (int i = 0; i < 4; i++)
#pragma unroll
        for (int j = 0; j < 4; j++)
          acc[i][j] = __builtin_amdgcn_mfma_f32_16x16x32_bf16(af[i], bfr[j], acc[i][j], 0, 0, 0);
    }
  }

#pragma unroll
  for (int i = 0; i < 4; i++)
#pragma unroll
    for (int j = 0; j < 4; j++) {
      int row = m0 + wm + i * 16 + qd * 4;
      int col = n0 + wn + j * 16 + l16;
      float bsv = bias ? bias[col] : 0.f;
#pragma unroll
      for (int r = 0; r < 4; r++) {
        float v = acc[i][j][r] + bsv;
        if (OUTF32) ((float*)Cout)[(size_t)(row + r) * N + col] = v;
        else ((unsigned short*)Cout)[(size_t)(row + r) * N + col] = f2bf(v);
      }
    }
}

// ---------------- RoPE + bias + rearrange q,k: qkv[BS,3D] -> [B,H,S,HD] ----------------
// q is pre-scaled by 1/sqrt(HD) so attention skips the scale multiply.
__global__ __launch_bounds__(256) void rope_qk(
    const unsigned short* __restrict__ qkv, const float* __restrict__ bq,
    const float* __restrict__ bk, unsigned short* __restrict__ q_r,
    unsigned short* __restrict__ k_r)
{
  int lin = blockIdx.x * 256 + threadIdx.x;
  int i = lin & 63;
  int s = (lin >> 6) & (SS - 1);
  int h = (lin >> 17) & (HH - 1);
  int b = lin >> 21;
  size_t row = (size_t)(b * SS + s) * (3 * DD);
  int f = h * HDD + i;
  float q1 = bf2f(qkv[row + f])            + bq[f];
  float q2 = bf2f(qkv[row + f + 64])       + bq[f + 64];
  float k1 = bf2f(qkv[row + DD + f])       + bk[f];
  float k2 = bf2f(qkv[row + DD + f + 64])  + bk[f + 64];
  float inv = powf(10000.f, -(float)i * (1.f / 64.f));
  float ang = (float)s * inv;
  float sn, c;
  sincosf(ang, &sn, &c);
  const float qs = 0.08838834764831845f;  // 1/sqrt(128)
  size_t ob = ((size_t)(b * HH + h) * SS + s) * HDD;
  q_r[ob + i]      = f2bf((q1 * c - q2 * sn) * qs);
  q_r[ob + i + 64] = f2bf((q1 * sn + q2 * c) * qs);
  k_r[ob + i]      = f2bf(k1 * c - k2 * sn);
  k_r[ob + i + 64] = f2bf(k1 * sn + k2 * c);
}

// ---------------- V transpose: qkv v-part -> v_t[B,H,HD,S'] (+bias) ----------------
// Key order is PERMUTED within each 64-key tile so the attention PV B-fragment
// (assembled in registers from softmax output) sees keys in MFMA k-slot order:
// kappa(y) = ((y>>5)&1)*32+((y>>2)&3)*8+((y>>4)&1)*4+(y&3)
__global__ __launch_bounds__(256) void v_transpose(
    const unsigned short* __restrict__ qkv, const float* __restrict__ bv,
    unsigned short* __restrict__ v_t)
{
  __shared__ float tile[32][33];
  int bh = blockIdx.z; int b = bh >> 4, h = bh & 15;
  int s0 = blockIdx.x * 32, d0 = blockIdx.y * 32;
  int tx = threadIdx.x, ty = threadIdx.y;
#pragma unroll
  for (int i = 0; i < 4; i++) {
    int s = s0 + ty + i * 8, dh = d0 + tx;
    tile[ty + i * 8][tx] =
        bf2f(qkv[(size_t)(b * SS + s) * (3 * DD) + 2 * DD + h * HDD + dh]) + bv[h * HDD + dh];
  }
  __syncthreads();
  int s = s0 + tx;
  int y = s & 63;
  int kap = ((y >> 5) & 1) * 32 + ((y >> 2) & 3) * 8 + ((y >> 4) & 1) * 4 + (y & 3);
  int scol = (s & ~63) + kap;
#pragma unroll
  for (int i = 0; i < 4; i++)
    v_t[((size_t)(b * HH + h) * HDD + d0 + ty + i * 8) * SS + scol] =
        f2bf(tile[tx][ty + i * 8]);
}

// ---------------- flash attention v4: dbuf staging + XCD swizzle ----------------
// grid: (S/128, B*H) = 512 blocks. Blocks remapped so all 16 q-tiles of one
// head land on one XCD (K/V L2 locality). K/V staging is double-buffered:
// next tile's global_load_lds issues right after the barrier and lands during
// the current tile's compute, so the vmcnt(0) barrier drain is free.
__global__ __launch_bounds__(256, 2) void attn_kernel(
    const unsigned short* __restrict__ q_r, const unsigned short* __restrict__ k_r,
    const unsigned short* __restrict__ v_t, unsigned short* __restrict__ aout)
{
  __shared__ unsigned short Ks[2][64 * 128];   // [key][hd], swizzled chunks
  __shared__ unsigned short Vs[2][128 * 64];   // [hd][key-slot], swizzled chunks
  int t = threadIdx.x, w = t >> 6, lane = t & 63, qd = lane >> 4, l16 = lane & 15;
  // XCD-aware remap: linear block L -> XCD x=L&7; head bh = x*4 + (L>>3)/16
  int L = blockIdx.y * gridDim.x + blockIdx.x;
  int jj = L >> 3;
  int bh = (L & 7) * 4 + (jj >> 4);
  int q0 = (jj & 15) * 128;
  const unsigned short* qb = q_r + (size_t)bh * SS * HDD;
  const unsigned short* kb = k_r + (size_t)bh * SS * HDD;
  const unsigned short* vb = v_t + (size_t)bh * HDD * SS;

  // persistent Q fragments (B-operand: lane l16 = qrow): 2 n-tiles x 4 k-steps
  short8 aq[2][4];
#pragma unroll
  for (int mi = 0; mi < 2; mi++)
#pragma unroll
    for (int ks = 0; ks < 4; ks++)
      aq[mi][ks] = *(const short8*)
          &qb[(size_t)(q0 + w * 32 + mi * 16 + l16) * HDD + ks * 32 + qd * 8];

  float m_i[2], l_i[2];
  floatx4 zero4 = {0.f, 0.f, 0.f, 0.f};
  floatx4 o[2][8];   // O^T: rows hd (8 blocks of 16), cols qrow (mi)
#pragma unroll
  for (int mi = 0; mi < 2; mi++) { m_i[mi] = -1e30f; l_i[mi] = 0.f; }
#pragma unroll
  for (int mi = 0; mi < 2; mi++)
#pragma unroll
    for (int n = 0; n < 8; n++) o[mi][n] = zero4;

  auto stage = [&](int nb, int kt) {
#pragma unroll
    for (int c = 0; c < 4; c++) {       // K tile: 64 rows x 128 elems
      int flat = c * 256 + t;
      int r = flat >> 4, cc = flat & 15;
      gl_lds16(kb + (size_t)(kt + r) * HDD + (cc ^ (r & 15)) * 8, &Ks[nb][flat * 8]);
    }
#pragma unroll
    for (int c = 0; c < 4; c++) {       // V^T tile: 128 rows x 64 slots
      int flat = c * 256 + t;
      int r = flat >> 3, cc = flat & 7;
      gl_lds16(vb + (size_t)r * SS + kt + (cc ^ (r & 7)) * 8, &Vs[nb][flat * 8]);
    }
  };

  stage(0, 0);
  int buf = 0;

  for (int kt = 0; kt < SS; kt += 64) {
    __syncthreads();                     // drains staging of `buf` (issued last iter)
    if (kt + 64 < SS) stage(buf ^ 1, kt + 64);   // prefetch next tile

    // ---- S^T = K.Q^T: rows = keys (4 j-blocks), cols = qrows (2 mi-blocks)
    floatx4 sc[2][4];
#pragma unroll
    for (int mi = 0; mi < 2; mi++)
#pragma unroll
      for (int j = 0; j < 4; j++) sc[mi][j] = zero4;
#pragma unroll
    for (int j = 0; j < 4; j++) {
      int krow = j * 16 + l16;
#pragma unroll
      for (int ks = 0; ks < 4; ks++) {
        int chunk = ks * 4 + qd;
        short8 kf = *(const short8*)&Ks[buf][krow * 128 + ((chunk ^ (krow & 15)) * 8)];
        sc[0][j] = __builtin_amdgcn_mfma_f32_16x16x32_bf16(kf, aq[0][ks], sc[0][j], 0, 0, 0);
        sc[1][j] = __builtin_amdgcn_mfma_f32_16x16x32_bf16(kf, aq[1][ks], sc[1][j], 0, 0, 0);
      }
    }
    // per lane: sc[mi][j][r] = S[qrow = q0+w*32+mi*16+l16][key = kt+16j+4qd+r]

    // ---- online softmax (per-lane 16-val reduce + xor16/xor32 shuffles)
    float rmax[2];
#pragma unroll
    for (int mi = 0; mi < 2; mi++) {
      float m = sc[mi][0][0];
#pragma unroll
      for (int j = 0; j < 4; j++)
#pragma unroll
        for (int r = 0; r < 4; r++) m = fmaxf(m, sc[mi][j][r]);
      m = fmaxf(m, __shfl_xor(m, 16, 64));
      m = fmaxf(m, __shfl_xor(m, 32, 64));
      rmax[mi] = m;
    }

    bool up = (rmax[0] > m_i[0]) || (rmax[1] > m_i[1]);
    if (__ballot(up) != 0ull) {
#pragma unroll
      for (int mi = 0; mi < 2; mi++) {
        float mn = fmaxf(m_i[mi], rmax[mi]);
        float a = __expf(m_i[mi] - mn);
        m_i[mi] = mn;
        l_i[mi] *= a;
#pragma unroll
        for (int n = 0; n < 8; n++)
#pragma unroll
          for (int r = 0; r < 4; r++) o[mi][n][r] *= a;
      }
    }

    // exp + pack bf16 pairs (adjacent keys r,r+1) -> P^T B-frag registers
    unsigned int pr[2][4][2];
#pragma unroll
    for (int mi = 0; mi < 2; mi++) {
      float s0 = 0.f;
#pragma unroll
      for (int j = 0; j < 4; j++) {
        float p0 = __expf(sc[mi][j][0] - m_i[mi]);
        float p1 = __expf(sc[mi][j][1] - m_i[mi]);
        float p2 = __expf(sc[mi][j][2] - m_i[mi]);
        float p3 = __expf(sc[mi][j][3] - m_i[mi]);
        s0 += (p0 + p1) + (p2 + p3);
        pr[mi][j][0] = pk2bf(p0, p1);
        pr[mi][j][1] = pk2bf(p2, p3);
      }
      s0 += __shfl_xor(s0, 16, 64);
      s0 += __shfl_xor(s0, 32, 64);
      l_i[mi] += s0;
    }

    // ---- PV: O^T += V^T . P^T  (B-frag = pr registers, key order matches V perm)
#pragma unroll
    for (int n = 0; n < 8; n++) {
      int vrow = n * 16 + l16;
#pragma unroll
      for (int ks = 0; ks < 2; ks++) {
        int chunk = ks * 4 + qd;
        short8 av = *(const short8*)&Vs[buf][vrow * 64 + ((chunk ^ (vrow & 7)) * 8)];
        union { unsigned int u[4]; short8 v; } bp0, bp1;
        bp0.u[0] = pr[0][2 * ks][0];     bp0.u[1] = pr[0][2 * ks][1];
        bp0.u[2] = pr[0][2 * ks + 1][0]; bp0.u[3] = pr[0][2 * ks + 1][1];
        bp1.u[0] = pr[1][2 * ks][0];     bp1.u[1] = pr[1][2 * ks][1];
        bp1.u[2] = pr[1][2 * ks + 1][0]; bp1.u[3] = pr[1][2 * ks + 1][1];
        o[0][n] = __builtin_amdgcn_mfma_f32_16x16x32_bf16(av, bp0.v, o[0][n], 0, 0, 0);
        o[1][n] = __builtin_amdgcn_mfma_f32_16x16x32_bf16(av, bp1.v, o[1][n], 0, 0, 0);
      }
    }
    buf ^= 1;
  }

  // epilogue: O^T cols -> aout rows; pack 4 bf16 (contiguous hd) per store
  int b = bh >> 4, h = bh & 15;
#pragma unroll
  for (int mi = 0; mi < 2; mi++) {
    int qrow = q0 + w * 32 + mi * 16 + l16;
    float inv_l = 1.f / l_i[mi];
    size_t base = ((size_t)(b * SS + qrow)) * DD + h * HDD;
#pragma unroll
    for (int n = 0; n < 8; n++) {
      uint2 pkd;
      pkd.x = pk2bf(o[mi][n][0] * inv_l, o[mi][n][1] * inv_l);
      pkd.y = pk2bf(o[mi][n][2] * inv_l, o[mi][n][3] * inv_l);
      *(uint2*)&aout[base + n * 16 + qd * 4] = pkd;
    }
  }
}

// ---------------- launch ----------------
extern "C" void kernel_launch(void* const* d_in, const int* in_sizes, int n_in,
                              void* d_out, int out_size, void* d_ws, size_t ws_size,
                              hipStream_t stream) {
  const float* x  = (const float*)d_in[0];
  const float* Wq = (const float*)d_in[1];
  const float* bq = (const float*)d_in[2];
  const float* Wk = (const float*)d_in[3];
  const float* bk = (const float*)d_in[4];
  const float* Wv = (const float*)d_in[5];
  const float* bv = (const float*)d_in[6];
  const float* Wo = (const float*)d_in[7];
  const float* bo = (const float*)d_in[8];
  float* out = (float*)d_out;

  char* ws = (char*)d_ws;
  // workspace layout (bytes); attn_out aliases xb (xb dead after QKV GEMM)
  unsigned short* xb      = (unsigned short*)(ws + 0);            // [BS,D] bf16, 16 MB
  unsigned short* wqkvt   = (unsigned short*)(ws + 16777216);     // [3D,D] bf16, 24 MB
  unsigned short* wot     = (unsigned short*)(ws + 41943040);     // [D,D]  bf16, 8 MB
  unsigned short* qkv     = (unsigned short*)(ws + 50331648);     // [BS,3D] bf16, 48 MB
  unsigned short* q_r     = (unsigned short*)(ws + 100663296);    // [B,H,S,HD] 16 MB
  unsigned short* k_r     = (unsigned short*)(ws + 117440512);    // [B,H,S,HD] 16 MB
  unsigned short* v_t     = (unsigned short*)(ws + 134217728);    // [B,H,HD,S] 16 MB
  unsigned short* attn_o  = xb;                                   // alias

  transpose_w<<<dim3(DD / 32, DD / 32, 4), dim3(32, 8), 0, stream>>>(
      Wq, Wk, Wv, Wo, wqkvt, wot);
  conv_x<<<dim3((BSR * DD) / 1024), dim3(256), 0, stream>>>(x, xb);
  gemm_bt<false><<<dim3(3 * DD / 128, BSR / 128), dim3(256), 0, stream>>>(
      xb, wqkvt, nullptr, qkv, BSR, 3 * DD, DD);
  rope_qk<<<dim3((BB * HH * SS * 64) / 256), dim3(256), 0, stream>>>(
      qkv, bq, bk, q_r, k_r);
  v_transpose<<<dim3(SS / 32, HDD / 32, BB * HH), dim3(32, 8), 0, stream>>>(
      qkv, bv, v_t);
  attn_kernel<<<dim3(SS / 128, BB * HH), dim3(256), 0, stream>>>(
      q_r, k_r, v_t, attn_o);
  gemm_bt<true><<<dim3(DD / 128, BSR / 128), dim3(256), 0, stream>>>(
      attn_o, wot, bo, out, BSR, DD, DD);
}

// Round 5
// 395.398 us; speedup vs baseline: 1.3999x; 1.1221x over previous
//
#include <hip/hip_runtime.h>

// Problem constants
#define BB  2
#define SS  2048
#define DD  2048
#define HH  16
#define HDD 128
#define BSR 4096   // BB*SS rows

using short8  = __attribute__((ext_vector_type(8))) short;
using floatx4 = __attribute__((ext_vector_type(4))) float;

__device__ __forceinline__ float bf2f(unsigned short u) {
  return __uint_as_float(((unsigned int)u) << 16);
}
__device__ __forceinline__ unsigned short f2bf(float f) {
  unsigned int u = __float_as_uint(f);
  u += 0x7fffu + ((u >> 16) & 1u);   // round-to-nearest-even
  return (unsigned short)(u >> 16);
}
// pack two floats -> two bf16 (rne) in one u32 (a=low, b=high)
__device__ __forceinline__ unsigned int pk2bf(float a, float b) {
  unsigned int ua = __float_as_uint(a);
  ua += 0x7fffu + ((ua >> 16) & 1u);
  unsigned int ub = __float_as_uint(b);
  ub += 0x7fffu + ((ub >> 16) & 1u);
  return (ua >> 16) | (ub & 0xffff0000u);
}
// fast 2^x (scores are kept in log2 domain)
__device__ __forceinline__ float fexp2(float x) {
#if __has_builtin(__builtin_amdgcn_exp2f)
  return __builtin_amdgcn_exp2f(x);
#else
  return __expf(x * 0.6931471805599453f);
#endif
}
// async global->LDS, 16 bytes per lane. LDS dest must be wave-uniform base + lane*16.
__device__ __forceinline__ void gl_lds16(const void* g, void* l) {
  __builtin_amdgcn_global_load_lds(
      (__attribute__((address_space(1))) void*)g,
      (__attribute__((address_space(3))) void*)l, 16, 0, 0);
}

// ---------------- weight transpose + bf16 convert: Out[f][d] = W[d][f] ----------------
__global__ __launch_bounds__(256) void transpose_w(
    const float* __restrict__ Wq, const float* __restrict__ Wk,
    const float* __restrict__ Wv, const float* __restrict__ Wo,
    unsigned short* __restrict__ wqkvt, unsigned short* __restrict__ wot)
{
  __shared__ float tile[32][33];
  const float* W; unsigned short* Out;
  int z = blockIdx.z;
  if      (z == 0) { W = Wq; Out = wqkvt; }
  else if (z == 1) { W = Wk; Out = wqkvt + (size_t)DD * DD; }
  else if (z == 2) { W = Wv; Out = wqkvt + 2 * (size_t)DD * DD; }
  else             { W = Wo; Out = wot; }
  int tx = threadIdx.x, ty = threadIdx.y;
  int d0 = blockIdx.y * 32, f0 = blockIdx.x * 32;
#pragma unroll
  for (int i = 0; i < 4; i++)
    tile[ty + i * 8][tx] = W[(size_t)(d0 + ty + i * 8) * DD + f0 + tx];
  __syncthreads();
#pragma unroll
  for (int i = 0; i < 4; i++)
    Out[(size_t)(f0 + ty + i * 8) * DD + d0 + tx] = f2bf(tile[tx][ty + i * 8]);
}

// ---------------- x -> bf16 ----------------
__global__ __launch_bounds__(256) void conv_x(const float* __restrict__ x,
                                              unsigned short* __restrict__ xb)
{
  size_t i = ((size_t)blockIdx.x * 256 + threadIdx.x) * 4;
  float4 v = *(const float4*)(x + i);
  ushort4 o;
  o.x = f2bf(v.x); o.y = f2bf(v.y); o.z = f2bf(v.z); o.w = f2bf(v.w);
  *(ushort4*)(xb + i) = o;
}

// ---------------- RoPE cos/sin table: rtab[s][c] = (cos, sin), s<2048, c<64 --------
__global__ __launch_bounds__(256) void rope_tab(float2* __restrict__ rtab) {
  int idx = blockIdx.x * 256 + threadIdx.x;   // 2048*64 entries
  int s = idx >> 6, c = idx & 63;
  float inv = powf(10000.f, -(float)c * (1.f / 64.f));
  float ang = (float)s * inv;
  float sn, cc;
  sincosf(ang, &sn, &cc);
  rtab[idx] = make_float2(cc, sn);
}

// ---------------- fused QKV GEMM + bias + RoPE + V-transpose ----------------
// C[4096,6144] = xb * wqkvt^T. 128x128 tile == exactly one (plane, head) column
// block. Epilogue round-trips the tile through LDS (stride 132 = +4 pad) and
// writes q_r/k_r (bias+RoPE, q prescaled by 1/sqrt(HD)*log2e) or v_t
// (bias + [hd][s] transpose with kappa key-permute) directly.
__global__ __launch_bounds__(256) void gemm_qkv(
    const unsigned short* __restrict__ A, const unsigned short* __restrict__ Bt,
    const float* __restrict__ bq, const float* __restrict__ bk,
    const float* __restrict__ bv, const float2* __restrict__ rtab,
    unsigned short* __restrict__ q_r, unsigned short* __restrict__ k_r,
    unsigned short* __restrict__ v_t)
{
  __shared__ unsigned short smem[16896];   // As(8192)|Bs(8192); reused as Ct[128][132]
  unsigned short* As = smem;
  unsigned short* Bs = smem + 8192;
  const int K = DD;
  int t = threadIdx.x;
  int m0 = blockIdx.y * 128, n0 = blockIdx.x * 128;
  int w = t >> 6, lane = t & 63, qd = lane >> 4, l16 = lane & 15;
  int wm = (w >> 1) * 64, wn = (w & 1) * 64;
  floatx4 zero4 = {0.f, 0.f, 0.f, 0.f};
  floatx4 acc[4][4];
#pragma unroll
  for (int i = 0; i < 4; i++)
#pragma unroll
    for (int j = 0; j < 4; j++) acc[i][j] = zero4;

  int gchunk = (t & 7) ^ ((t >> 3) & 7);
  const unsigned short* Ab = A  + (size_t)(m0 + (t >> 3)) * K + gchunk * 8;
  const unsigned short* Bb = Bt + (size_t)(n0 + (t >> 3)) * K + gchunk * 8;
  size_t qK = (size_t)32 * K;

  for (int k0 = 0; k0 < K; k0 += 64) {
    __syncthreads();
#pragma unroll
    for (int c = 0; c < 4; c++) {
      gl_lds16(Ab + c * qK + k0, &As[(c * 256 + t) * 8]);
      gl_lds16(Bb + c * qK + k0, &Bs[(c * 256 + t) * 8]);
    }
    __syncthreads();
#pragma unroll
    for (int ks = 0; ks < 2; ks++) {
      int ch = ((ks * 4 + qd) ^ (l16 & 7)) * 8;
      short8 af[4], bfr[4];
#pragma unroll
      for (int i = 0; i < 4; i++)
        af[i] = *(const short8*)&As[(wm + i * 16 + l16) * 64 + ch];
#pragma unroll
      for (int j = 0; j < 4; j++)
        bfr[j] = *(const short8*)&Bs[(wn + j * 16 + l16) * 64 + ch];
#pragma unroll
      for (int i = 0; i < 4; i++)
#pragma unroll
        for (int j = 0; j < 4; j++)
          acc[i][j] = __builtin_amdgcn_mfma_f32_16x16x32_bf16(af[i], bfr[j], acc[i][j], 0, 0, 0);
    }
  }

  // ---- epilogue ----
  int plane = n0 >> 11;            // 0=q, 1=k, 2=v
  int h = (n0 >> 7) & 15;
  const float* bias = plane == 0 ? bq : (plane == 1 ? bk : bv);
  __syncthreads();                 // all waves done reading As/Bs
#pragma unroll
  for (int i = 0; i < 4; i++)
#pragma unroll
    for (int j = 0; j < 4; j++) {
      int rl = wm + i * 16 + qd * 4;
      int cl = wn + j * 16 + l16;
      float bsv = bias[h * 128 + cl];
#pragma unroll
      for (int r = 0; r < 4; r++)
        smem[(rl + r) * 132 + cl] = f2bf(acc[i][j][r] + bsv);
    }
  __syncthreads();

  int b = m0 >> 11, sbase = m0 & (SS - 1);
  if (plane < 2) {
    unsigned short* dst = (plane == 0 ? q_r : k_r) + (size_t)(b * HH + h) * SS * HDD;
    // q prescale: 1/sqrt(128) * log2(e); k unscaled
    const float fac = (plane == 0) ? 0.12751744f : 1.0f;
#pragma unroll
    for (int it = 0; it < 16; it++) {
      int idx = it * 256 + t;
      int rl = idx >> 5, c2 = (idx & 31) * 2;
      int s = sbase + rl;
      float4 cs = *(const float4*)&rtab[(size_t)s * 64 + c2]; // cos0,sin0,cos1,sin1
      float a0 = bf2f(smem[rl * 132 + c2]);
      float a1 = bf2f(smem[rl * 132 + c2 + 1]);
      float b0 = bf2f(smem[rl * 132 + c2 + 64]);
      float b1 = bf2f(smem[rl * 132 + c2 + 65]);
      unsigned int lo = pk2bf((a0 * cs.x - b0 * cs.y) * fac,
                              (a1 * cs.z - b1 * cs.w) * fac);
      unsigned int hi = pk2bf((a0 * cs.y + b0 * cs.x) * fac,
                              (a1 * cs.w + b1 * cs.z) * fac);
      size_t rowb = (size_t)s * HDD;
      *(unsigned int*)&dst[rowb + c2]      = lo;
      *(unsigned int*)&dst[rowb + c2 + 64] = hi;
    }
  } else {
    // v: transpose to [hd][s] with kappa key-permute within each 64-block
    unsigned short* dst = v_t + (size_t)(b * HH + h) * HDD * SS;
#pragma unroll
    for (int it = 0; it < 32; it++) {
      int idx = it * 256 + t;
      int hd = idx >> 6, sp = (idx & 63) * 2;
      unsigned short v0 = smem[sp * 132 + hd];
      unsigned short v1 = smem[(sp + 1) * 132 + hd];
      int y = sp & 63;
      int kap = ((y >> 5) & 1) * 32 + ((y >> 2) & 3) * 8 + ((y >> 4) & 1) * 4 + (y & 3);
      int sg = sbase + (sp & ~63) + kap;
      *(unsigned int*)&dst[(size_t)hd * SS + sg] = ((unsigned int)v1 << 16) | v0;
    }
  }
}

// ---------------- bf16 MFMA GEMM, B^T layout, BK=64 (final projection) -----------
template <bool OUTF32>
__global__ __launch_bounds__(256) void gemm_bt(
    const unsigned short* __restrict__ A, const unsigned short* __restrict__ Bt,
    const float* __restrict__ bias, void* __restrict__ Cout,
    int M, int N, int K)
{
  __shared__ unsigned short As[128 * 64];
  __shared__ unsigned short Bs[128 * 64];
  int t = threadIdx.x;
  int m0 = blockIdx.y * 128, n0 = blockIdx.x * 128;
  int w = t >> 6, lane = t & 63, qd = lane >> 4, l16 = lane & 15;
  int wm = (w >> 1) * 64, wn = (w & 1) * 64;
  floatx4 zero4 = {0.f, 0.f, 0.f, 0.f};
  floatx4 acc[4][4];
#pragma unroll
  for (int i = 0; i < 4; i++)
#pragma unroll
    for (int j = 0; j < 4; j++) acc[i][j] = zero4;

  int gchunk = (t & 7) ^ ((t >> 3) & 7);
  const unsigned short* Ab = A  + (size_t)(m0 + (t >> 3)) * K + gchunk * 8;
  const unsigned short* Bb = Bt + (size_t)(n0 + (t >> 3)) * K + gchunk * 8;
  size_t qK = (size_t)32 * K;

  for (int k0 = 0; k0 < K; k0 += 64) {
    __syncthreads();
#pragma unroll
    for (int c = 0; c < 4; c++) {
      gl_lds16(Ab + c * qK + k0, &As[(c * 256 + t) * 8]);
      gl_lds16(Bb + c * qK + k0, &Bs[(c * 256 + t) * 8]);
    }
    __syncthreads();
#pragma unroll
    for (int ks = 0; ks < 2; ks++) {
      int ch = ((ks * 4 + qd) ^ (l16 & 7)) * 8;
      short8 af[4], bfr[4];
#pragma unroll
      for (int i = 0; i < 4; i++)
        af[i] = *(const short8*)&As[(wm + i * 16 + l16) * 64 + ch];
#pragma unroll
      for (int j = 0; j < 4; j++)
        bfr[j] = *(const short8*)&Bs[(wn + j * 16 + l16) * 64 + ch];
#pragma unroll
      for (int i = 0; i < 4; i++)
#pragma unroll
        for (int j = 0; j < 4; j++)
          acc[i][j] = __builtin_amdgcn_mfma_f32_16x16x32_bf16(af[i], bfr[j], acc[i][j], 0, 0, 0);
    }
  }

#pragma unroll
  for (int i = 0; i < 4; i++)
#pragma unroll
    for (int j = 0; j < 4; j++) {
      int row = m0 + wm + i * 16 + qd * 4;
      int col = n0 + wn + j * 16 + l16;
      float bsv = bias ? bias[col] : 0.f;
#pragma unroll
      for (int r = 0; r < 4; r++) {
        float v = acc[i][j][r] + bsv;
        if (OUTF32) ((float*)Cout)[(size_t)(row + r) * N + col] = v;
        else ((unsigned short*)Cout)[(size_t)(row + r) * N + col] = f2bf(v);
      }
    }
}

// ---------------- flash attention v5: dbuf staging + XCD swizzle + exp2 ----------
// Scores arrive in log2 domain (q pre-scaled by 1/sqrt(HD)*log2e), so softmax
// uses native v_exp_f32 (2^x) with no per-exp multiply.
__global__ __launch_bounds__(256, 2) void attn_kernel(
    const unsigned short* __restrict__ q_r, const unsigned short* __restrict__ k_r,
    const unsigned short* __restrict__ v_t, unsigned short* __restrict__ aout)
{
  __shared__ unsigned short Ks[2][64 * 128];   // [key][hd], swizzled chunks
  __shared__ unsigned short Vs[2][128 * 64];   // [hd][key-slot], swizzled chunks
  int t = threadIdx.x, w = t >> 6, lane = t & 63, qd = lane >> 4, l16 = lane & 15;
  // XCD-aware remap: all 16 q-tiles of one head land on one XCD
  int L = blockIdx.y * gridDim.x + blockIdx.x;
  int jj = L >> 3;
  int bh = (L & 7) * 4 + (jj >> 4);
  int q0 = (jj & 15) * 128;
  const unsigned short* qb = q_r + (size_t)bh * SS * HDD;
  const unsigned short* kb = k_r + (size_t)bh * SS * HDD;
  const unsigned short* vb = v_t + (size_t)bh * HDD * SS;

  short8 aq[2][4];
#pragma unroll
  for (int mi = 0; mi < 2; mi++)
#pragma unroll
    for (int ks = 0; ks < 4; ks++)
      aq[mi][ks] = *(const short8*)
          &qb[(size_t)(q0 + w * 32 + mi * 16 + l16) * HDD + ks * 32 + qd * 8];

  float m_i[2], l_i[2];
  floatx4 zero4 = {0.f, 0.f, 0.f, 0.f};
  floatx4 o[2][8];   // O^T: rows hd (8 blocks of 16), cols qrow (mi)
#pragma unroll
  for (int mi = 0; mi < 2; mi++) { m_i[mi] = -1e30f; l_i[mi] = 0.f; }
#pragma unroll
  for (int mi = 0; mi < 2; mi++)
#pragma unroll
    for (int n = 0; n < 8; n++) o[mi][n] = zero4;

  auto stage = [&](int nb, int kt) {
#pragma unroll
    for (int c = 0; c < 4; c++) {       // K tile: 64 rows x 128 elems
      int flat = c * 256 + t;
      int r = flat >> 4, cc = flat & 15;
      gl_lds16(kb + (size_t)(kt + r) * HDD + (cc ^ (r & 15)) * 8, &Ks[nb][flat * 8]);
    }
#pragma unroll
    for (int c = 0; c < 4; c++) {       // V^T tile: 128 rows x 64 slots
      int flat = c * 256 + t;
      int r = flat >> 3, cc = flat & 7;
      gl_lds16(vb + (size_t)r * SS + kt + (cc ^ (r & 7)) * 8, &Vs[nb][flat * 8]);
    }
  };

  stage(0, 0);
  int buf = 0;

  for (int kt = 0; kt < SS; kt += 64) {
    __syncthreads();                     // drains staging of `buf`
    if (kt + 64 < SS) stage(buf ^ 1, kt + 64);   // prefetch next tile

    floatx4 sc[2][4];
#pragma unroll
    for (int mi = 0; mi < 2; mi++)
#pragma unroll
      for (int j = 0; j < 4; j++) sc[mi][j] = zero4;
#pragma unroll
    for (int j = 0; j < 4; j++) {
      int krow = j * 16 + l16;
#pragma unroll
      for (int ks = 0; ks < 4; ks++) {
        int chunk = ks * 4 + qd;
        short8 kf = *(const short8*)&Ks[buf][krow * 128 + ((chunk ^ (krow & 15)) * 8)];
        sc[0][j] = __builtin_amdgcn_mfma_f32_16x16x32_bf16(kf, aq[0][ks], sc[0][j], 0, 0, 0);
        sc[1][j] = __builtin_amdgcn_mfma_f32_16x16x32_bf16(kf, aq[1][ks], sc[1][j], 0, 0, 0);
      }
    }

    float rmax[2];
#pragma unroll
    for (int mi = 0; mi < 2; mi++) {
      float m = sc[mi][0][0];
#pragma unroll
      for (int j = 0; j < 4; j++)
#pragma unroll
        for (int r = 0; r < 4; r++) m = fmaxf(m, sc[mi][j][r]);
      m = fmaxf(m, __shfl_xor(m, 16, 64));
      m = fmaxf(m, __shfl_xor(m, 32, 64));
      rmax[mi] = m;
    }

    bool up = (rmax[0] > m_i[0]) || (rmax[1] > m_i[1]);
    if (__ballot(up) != 0ull) {
#pragma unroll
      for (int mi = 0; mi < 2; mi++) {
        float mn = fmaxf(m_i[mi], rmax[mi]);
        float a = fexp2(m_i[mi] - mn);
        m_i[mi] = mn;
        l_i[mi] *= a;
#pragma unroll
        for (int n = 0; n < 8; n++)
#pragma unroll
          for (int r = 0; r < 4; r++) o[mi][n][r] *= a;
      }
    }

    unsigned int pr[2][4][2];
#pragma unroll
    for (int mi = 0; mi < 2; mi++) {
      float s0 = 0.f;
#pragma unroll
      for (int j = 0; j < 4; j++) {
        float p0 = fexp2(sc[mi][j][0] - m_i[mi]);
        float p1 = fexp2(sc[mi][j][1] - m_i[mi]);
        float p2 = fexp2(sc[mi][j][2] - m_i[mi]);
        float p3 = fexp2(sc[mi][j][3] - m_i[mi]);
        s0 += (p0 + p1) + (p2 + p3);
        pr[mi][j][0] = pk2bf(p0, p1);
        pr[mi][j][1] = pk2bf(p2, p3);
      }
      s0 += __shfl_xor(s0, 16, 64);
      s0 += __shfl_xor(s0, 32, 64);
      l_i[mi] += s0;
    }

#pragma unroll
    for (int n = 0; n < 8; n++) {
      int vrow = n * 16 + l16;
#pragma unroll
      for (int ks = 0; ks < 2; ks++) {
        int chunk = ks * 4 + qd;
        short8 av = *(const short8*)&Vs[buf][vrow * 64 + ((chunk ^ (vrow & 7)) * 8)];
        union { unsigned int u[4]; short8 v; } bp0, bp1;
        bp0.u[0] = pr[0][2 * ks][0];     bp0.u[1] = pr[0][2 * ks][1];
        bp0.u[2] = pr[0][2 * ks + 1][0]; bp0.u[3] = pr[0][2 * ks + 1][1];
        bp1.u[0] = pr[1][2 * ks][0];     bp1.u[1] = pr[1][2 * ks][1];
        bp1.u[2] = pr[1][2 * ks + 1][0]; bp1.u[3] = pr[1][2 * ks + 1][1];
        o[0][n] = __builtin_amdgcn_mfma_f32_16x16x32_bf16(av, bp0.v, o[0][n], 0, 0, 0);
        o[1][n] = __builtin_amdgcn_mfma_f32_16x16x32_bf16(av, bp1.v, o[1][n], 0, 0, 0);
      }
    }
    buf ^= 1;
  }

  int b = bh >> 4, h = bh & 15;
#pragma unroll
  for (int mi = 0; mi < 2; mi++) {
    int qrow = q0 + w * 32 + mi * 16 + l16;
    float inv_l = 1.f / l_i[mi];
    size_t base = ((size_t)(b * SS + qrow)) * DD + h * HDD;
#pragma unroll
    for (int n = 0; n < 8; n++) {
      uint2 pkd;
      pkd.x = pk2bf(o[mi][n][0] * inv_l, o[mi][n][1] * inv_l);
      pkd.y = pk2bf(o[mi][n][2] * inv_l, o[mi][n][3] * inv_l);
      *(uint2*)&aout[base + n * 16 + qd * 4] = pkd;
    }
  }
}

// ---------------- launch ----------------
extern "C" void kernel_launch(void* const* d_in, const int* in_sizes, int n_in,
                              void* d_out, int out_size, void* d_ws, size_t ws_size,
                              hipStream_t stream) {
  const float* x  = (const float*)d_in[0];
  const float* Wq = (const float*)d_in[1];
  const float* bq = (const float*)d_in[2];
  const float* Wk = (const float*)d_in[3];
  const float* bk = (const float*)d_in[4];
  const float* Wv = (const float*)d_in[5];
  const float* bv = (const float*)d_in[6];
  const float* Wo = (const float*)d_in[7];
  const float* bo = (const float*)d_in[8];
  float* out = (float*)d_out;

  char* ws = (char*)d_ws;
  unsigned short* xb      = (unsigned short*)(ws + 0);            // [BS,D] bf16, 16 MB
  unsigned short* wqkvt   = (unsigned short*)(ws + 16777216);     // [3D,D] bf16, 24 MB
  unsigned short* wot     = (unsigned short*)(ws + 41943040);     // [D,D]  bf16, 8 MB
  float2*         rtab    = (float2*)(ws + 50331648);             // [S,64] f32x2, 1 MB
  unsigned short* q_r     = (unsigned short*)(ws + 100663296);    // [B,H,S,HD] 16 MB
  unsigned short* k_r     = (unsigned short*)(ws + 117440512);    // [B,H,S,HD] 16 MB
  unsigned short* v_t     = (unsigned short*)(ws + 134217728);    // [B,H,HD,S] 16 MB
  unsigned short* attn_o  = xb;   // alias: xb dead after gemm_qkv

  transpose_w<<<dim3(DD / 32, DD / 32, 4), dim3(32, 8), 0, stream>>>(
      Wq, Wk, Wv, Wo, wqkvt, wot);
  conv_x<<<dim3((BSR * DD) / 1024), dim3(256), 0, stream>>>(x, xb);
  rope_tab<<<dim3((SS * 64) / 256), dim3(256), 0, stream>>>(rtab);
  gemm_qkv<<<dim3(3 * DD / 128, BSR / 128), dim3(256), 0, stream>>>(
      xb, wqkvt, bq, bk, bv, rtab, q_r, k_r, v_t);
  attn_kernel<<<dim3(SS / 128, BB * HH), dim3(256), 0, stream>>>(
      q_r, k_r, v_t, attn_o);
  gemm_bt<true><<<dim3(DD / 128, BSR / 128), dim3(256), 0, stream>>>(
      attn_o, wot, bo, out, BSR, DD, DD);
}